// Round 11
// baseline (1195.549 us; speedup 1.0000x reference)
//
#include <hip/hip_runtime.h>
#include <stdint.h>

#define NB   256      // batch
#define NS   196      // seq len (= hidden seq)
#define NF   384      // in/out features
#define NH   8        // heads
#define NEH  48       // per-head dim
#define NIT  10
#define SP   224      // padded seq (14 tiles of 16)
#define EP   64       // padded per-head dim
#define NBH  2048     // NB*NH
#define NBS  50176    // NB*NS
#define NT   13       // inp tiles (rows<196 only)

using f32x4  = __attribute__((ext_vector_type(4))) float;
using u16x8  = __attribute__((ext_vector_type(8))) uint16_t;
using u16x4  = __attribute__((ext_vector_type(4))) uint16_t;
using bf16x8 = __attribute__((ext_vector_type(8))) __bf16;

static __device__ __forceinline__ float bf2f(uint16_t u){
  union { uint32_t u32; float f; } c; c.u32 = (uint32_t)u << 16; return c.f;
}
static __device__ __forceinline__ uint16_t f2bf(float f){
  __bf16 h = (__bf16)f;
  return __builtin_bit_cast(uint16_t, h);
}
static __device__ __forceinline__ float frcp(float f){
  return __builtin_amdgcn_rcpf(f);
}
static __device__ __forceinline__ bf16x8 ld8(const uint16_t* p){
  return __builtin_bit_cast(bf16x8, *(const u16x8*)p);
}
static __device__ __forceinline__ void lds_fence(){
  asm volatile("s_waitcnt lgkmcnt(0)" ::: "memory");
}
// 16-lane sum via DPP (4 VALU adds, no LDS traffic)
static __device__ __forceinline__ float dpp_add16(float x){
  int v = __builtin_bit_cast(int, x);
  x += __builtin_bit_cast(float, __builtin_amdgcn_update_dpp(0, v, 0xB1, 0xF, 0xF, false));
  v = __builtin_bit_cast(int, x);
  x += __builtin_bit_cast(float, __builtin_amdgcn_update_dpp(0, v, 0x4E, 0xF, 0xF, false));
  v = __builtin_bit_cast(int, x);
  x += __builtin_bit_cast(float, __builtin_amdgcn_update_dpp(0, v, 0x141, 0xF, 0xF, false));
  v = __builtin_bit_cast(int, x);
  x += __builtin_bit_cast(float, __builtin_amdgcn_update_dpp(0, v, 0x140, 0xF, 0xF, false));
  return x;
}
#define MFMA16(a,b,c) __builtin_amdgcn_mfma_f32_16x16x32_bf16((a),(b),(c),0,0,0)

// ---------------- prep kernels ----------------

__global__ void k_prep_gw(const float* __restrict__ gw, uint16_t* __restrict__ gw_b,
                          uint16_t* __restrict__ gwt_b){
  int idx = blockIdx.x * 256 + threadIdx.x;
  if (idx >= NH*SP*SP) return;
  int h = idx / (SP*SP);
  int r = (idx / SP) % SP;   // o
  int c = idx % SP;          // i
  float v = (r < NS && c < NS) ? gw[((size_t)h*NS + r)*NS + c] : 0.f;
  uint16_t bv = f2bf(v);
  gw_b[idx] = bv;
  gwt_b[((size_t)h*SP + c)*SP + r] = bv;
}

__global__ void k_prep_small(const float* __restrict__ lw, const float* __restrict__ ew,
                             const float* __restrict__ ow,
                             uint16_t* __restrict__ lw_b, uint16_t* __restrict__ lwt_b,
                             uint16_t* __restrict__ ew_b, uint16_t* __restrict__ ow_b){
  int idx = blockIdx.x * 256 + threadIdx.x;
  if (idx < EP*EP){
    int f = idx >> 6, e = idx & 63;
    float v = (f < NEH && e < NEH) ? lw[f*NEH + e] : 0.f;
    uint16_t bv = f2bf(v);
    lw_b[f*EP + e] = bv;     // [f][e]
    lwt_b[e*EP + f] = bv;    // [e][f]
  }
  if (idx < NF*NF){
    ew_b[idx] = f2bf(ew[idx]);
    ow_b[idx] = f2bf(ow[idx]);
  }
}

// ---------------- embed GEMM + input prep ----------------
// 8 waves; inp FRAGMENT-MAJOR: inp_fm[bh][t][lane][slot], slot=j*4+r.
// Stores VECTORIZED u16x4 (validated r9/r10).
__global__ __launch_bounds__(512) void k_embed(const float* __restrict__ x,
    const uint16_t* __restrict__ ew_b, const float* __restrict__ eb,
    uint16_t* __restrict__ inp_fm){
  const int wave = threadIdx.x >> 6, lane = threadIdx.x & 63;
  const int lg = lane >> 4, li = lane & 15;
  const int mt = wave >> 1, nh = wave & 1;
  const int m0 = blockIdx.x * 64 + mt * 16;
  f32x4 acc[12];
  #pragma unroll
  for (int i = 0; i < 12; ++i) acc[i] = (f32x4)0.0f;
  const float* ap = x + (size_t)(m0 + li) * NF + 8*lg;
  for (int kt = 0; kt < 12; ++kt){
    f32x4 a0 = *(const f32x4*)(ap + kt*32);
    f32x4 a1 = *(const f32x4*)(ap + kt*32 + 4);
    u16x8 au;
    #pragma unroll
    for (int j = 0; j < 4; ++j){ au[j] = f2bf(a0[j]); au[j+4] = f2bf(a1[j]); }
    bf16x8 a = __builtin_bit_cast(bf16x8, au);
    #pragma unroll
    for (int nt = 0; nt < 12; ++nt){
      bf16x8 b = ld8(ew_b + (size_t)((nh*12 + nt)*16 + li)*NF + kt*32 + 8*lg);
      acc[nt] = MFMA16(a, b, acc[nt]);
    }
  }
  const int mbase = m0 + 4*lg;
  const int b  = mbase / NS;
  const int si = mbase - b*NS;
  const int t  = si >> 4, wi = si & 15;
  const int lanep = (wi >> 2)*16 + li;
  #pragma unroll
  for (int hl = 0; hl < 4; ++hl){
    int hh = nh*4 + hl;
    float xec[3][4];
    float s[4] = {0.f, 0.f, 0.f, 0.f};
    #pragma unroll
    for (int j = 0; j < 3; ++j){
      int nt = hl*3 + j;
      float bias = eb[(nh*12 + nt)*16 + li];
      #pragma unroll
      for (int r = 0; r < 4; ++r){
        float v = fmaxf(acc[nt][r] + bias, 1e-6f);
        xec[j][r] = v; s[r] += v;
      }
    }
    #pragma unroll
    for (int r = 0; r < 4; ++r) s[r] = frcp(dpp_add16(s[r]));
    uint16_t* dst = inp_fm + ((size_t)((b*NH + hh)*NT + t)*64 + lanep)*12;
    #pragma unroll
    for (int j = 0; j < 3; ++j){
      u16x4 w;
      #pragma unroll
      for (int r = 0; r < 4; ++r) w[r] = f2bf(xec[j][r] * s[r]);
      *(u16x4*)(dst + j*4) = w;    // 8B-aligned (lanep*24 % 8 == 0)
    }
  }
}

// ---------------- main NNMF fixed-point kernel ----------------
// 2-BATCH MEGA-BLOCK (r11): grid 1024, 896 thr = 14 waves. Waves 0-6 handle
// batch 2bp, waves 7-13 handle 2bp+1 -- SAME head, so both halves read the
// SAME gw/gwt A-fragments (halves the 4.1 GB -> 2.05 GB L2 gw traffic that
// was ~27% of k_main; wave-pairs also L1-hit each other's lines). Per-wave
// code identical to the measured-443us r8 structure (balanced 2 tiles/wave,
// unconditional dual-tile bodies). LDS 153.6 KB -> 1 block/CU = 14 waves
// (same occupancy as r10's 2x7). head = blockIdx&7 keeps per-XCD
// single-head L2 locality under round-robin dispatch.
__global__ __launch_bounds__(896) void k_main(
    const float*    __restrict__ h0,     // [B][NS][H][NEH]
    const uint16_t* __restrict__ gw_b,   // [H][SP][SP] (o,i)
    const uint16_t* __restrict__ gwt_b,  // [H][SP][SP] (i,o)
    const uint16_t* __restrict__ lw_b,   // [EP][EP] (f,e)
    const uint16_t* __restrict__ lwt_b,  // [EP][EP] (e,f)
    const uint16_t* __restrict__ inp_fm, // [BH][13][64][12]
    uint16_t* __restrict__ h_b)          // [BH][SP][EP] (for k_out)
{
  __shared__ __align__(16) uint16_t hlT[2][48][232];     // per half
  __shared__ __align__(16) uint16_t t2T[2][48][232];     // per half
  __shared__ __align__(16) uint16_t Sg[14][2][16][72];   // per-wave staging

  const int hh = blockIdx.x & 7;
  const int bp = blockIdx.x >> 3;
  const int tid = threadIdx.x;
  const int wave = tid >> 6;           // 0..13
  const int half = (wave >= 7) ? 1 : 0;
  const int wl   = wave - half*7;      // 0..6 within half
  const int b    = bp*2 + half;
  const int bh   = b*NH + hh;
  const int lane = tid & 63;
  const int lg = lane >> 4;
  const int li = lane & 15;
  const int tt[2] = {wl, wl + 7};

  // zero staging K-pad cols 48..63 (never rewritten; kt=1 A-frag reads them)
  {
    u16x4 z = {0,0,0,0};
    *(u16x4*)&Sg[wave][0][li][48 + 4*lg] = z;
    *(u16x4*)&Sg[wave][1][li][48 + 4*lg] = z;
  }

  // local-weight B-fragments (constant across iterations)
  bf16x8 lwtF[3][2], lwF[3][2];
  #pragma unroll
  for (int nt = 0; nt < 3; ++nt)
    #pragma unroll
    for (int kt = 0; kt < 2; ++kt){
      lwtF[nt][kt] = ld8(lwt_b + (size_t)(nt*16 + li)*EP + kt*32 + 8*lg); // B[k=f][n=e]
      lwF [nt][kt] = ld8(lw_b  + (size_t)(nt*16 + li)*EP + kt*32 + 8*lg); // B[k=e][n=f]
    }

  // persistent inp fragments (iteration-invariant): pad tile 13 -> zeros
  u16x4 ip[2][3];
  #pragma unroll
  for (int tp = 0; tp < 2; ++tp){
    const int t = tt[tp];
    if (t < NT){
      const uint16_t* ipp = inp_fm + ((size_t)(bh*NT + t)*64 + lg*16 + li)*12;
      ip[tp][0] = *(const u16x4*)(ipp);
      ip[tp][1] = *(const u16x4*)(ipp + 4);
      ip[tp][2] = *(const u16x4*)(ipp + 8);
    } else {
      u16x4 z = {0,0,0,0};
      ip[tp][0] = z; ip[tp][1] = z; ip[tp][2] = z;
    }
  }

  // h init straight from h0 (fp32): fragment layout row=t*16+4lg+r,
  // col=nt*16+li; L1-normalize per row via dpp_add16; stage bf16 to Sg
  float hr[2][3][4];
  #pragma unroll
  for (int tp = 0; tp < 2; ++tp){
    const int t = tt[tp];
    float s[4] = {0.f,0.f,0.f,0.f};
    #pragma unroll
    for (int nt = 0; nt < 3; ++nt)
      #pragma unroll
      for (int r = 0; r < 4; ++r){
        int row = t*16 + 4*lg + r;
        float v = 0.f;
        if (row < NS)
          v = h0[(((size_t)(b*NS + row))*NH + hh)*NEH + nt*16 + li];
        hr[tp][nt][r] = v;
        s[r] += fabsf(v);
      }
    #pragma unroll
    for (int r = 0; r < 4; ++r) s[r] = frcp(fmaxf(dpp_add16(s[r]), 1e-12f));
    #pragma unroll
    for (int nt = 0; nt < 3; ++nt)
      #pragma unroll
      for (int r = 0; r < 4; ++r){
        hr[tp][nt][r] *= s[r];
        Sg[wave][tp][4*lg + r][nt*16 + li] = f2bf(hr[tp][nt][r]);
      }
  }
  lds_fence();
  // initial hl = h x lw -> hlT
  #pragma unroll
  for (int tp = 0; tp < 2; ++tp){
    const int t = tt[tp];
    f32x4 hl[3];
    #pragma unroll
    for (int i = 0; i < 3; ++i) hl[i] = (f32x4)0.0f;
    #pragma unroll
    for (int kt = 0; kt < 2; ++kt){
      bf16x8 a = ld8(&Sg[wave][tp][li][kt*32 + 8*lg]);
      #pragma unroll
      for (int nt = 0; nt < 3; ++nt) hl[nt] = MFMA16(a, lwtF[nt][kt], hl[nt]);
    }
    #pragma unroll
    for (int nt = 0; nt < 3; ++nt){
      u16x4 w;
      #pragma unroll
      for (int r = 0; r < 4; ++r) w[r] = f2bf(hl[nt][r]);
      *(u16x4*)&hlT[half][nt*16 + li][t*16 + 4*lg] = w;
    }
  }

  const uint16_t* __restrict__ gwh  = gw_b  + (size_t)hh * SP * SP;
  const uint16_t* __restrict__ gwth = gwt_b + (size_t)hh * SP * SP;
  const uint16_t* gA0t = gwth + (size_t)(tt[0]*16 + li)*SP + 8*lg;
  const uint16_t* gA1t = gwth + (size_t)(tt[1]*16 + li)*SP + 8*lg;
  const uint16_t* gA0  = gwh  + (size_t)(tt[0]*16 + li)*SP + 8*lg;
  const uint16_t* gA1  = gwh  + (size_t)(tt[1]*16 + li)*SP + 8*lg;
  __syncthreads();   // hlT ready

  for (int it = 0; it < NIT; ++it){
    // ---- phase B: rec = gwt x hlT (B-frags shared across tiles)
    f32x4 rec[2][3];
    #pragma unroll
    for (int tp = 0; tp < 2; ++tp)
      #pragma unroll
      for (int i = 0; i < 3; ++i) rec[tp][i] = (f32x4)0.0f;
    #pragma unroll
    for (int kt = 0; kt < 7; ++kt){
      bf16x8 b0 = ld8(&hlT[half][ 0 + li][kt*32 + 8*lg]);
      bf16x8 b1 = ld8(&hlT[half][16 + li][kt*32 + 8*lg]);
      bf16x8 b2 = ld8(&hlT[half][32 + li][kt*32 + 8*lg]);
      bf16x8 a0 = ld8(gA0t + kt*32);
      bf16x8 a1 = ld8(gA1t + kt*32);
      rec[0][0] = MFMA16(a0, b0, rec[0][0]);
      rec[0][1] = MFMA16(a0, b1, rec[0][1]);
      rec[0][2] = MFMA16(a0, b2, rec[0][2]);
      rec[1][0] = MFMA16(a1, b0, rec[1][0]);
      rec[1][1] = MFMA16(a1, b1, rec[1][1]);
      rec[1][2] = MFMA16(a1, b2, rec[1][2]);
    }
    #pragma unroll
    for (int tp = 0; tp < 2; ++tp){
      float s[4] = {0.f,0.f,0.f,0.f};
      float rv[3][4];
      #pragma unroll
      for (int nt = 0; nt < 3; ++nt)
        #pragma unroll
        for (int r = 0; r < 4; ++r){
          float v = fmaxf(rec[tp][nt][r], 1e-6f);
          rv[nt][r] = v; s[r] += v;
        }
      #pragma unroll
      for (int r = 0; r < 4; ++r) s[r] = dpp_add16(s[r]);
      #pragma unroll
      for (int r = 0; r < 4; ++r){
        Sg[wave][tp][4*lg + r][ 0 + li] = f2bf(bf2f(ip[tp][0][r]) * s[r] * frcp(rv[0][r]));
        Sg[wave][tp][4*lg + r][16 + li] = f2bf(bf2f(ip[tp][1][r]) * s[r] * frcp(rv[1][r]));
        Sg[wave][tp][4*lg + r][32 + li] = f2bf(bf2f(ip[tp][2][r]) * s[r] * frcp(rv[2][r]));
      }
    }
    lds_fence();
    #pragma unroll
    for (int tp = 0; tp < 2; ++tp){
      const int t = tt[tp];
      f32x4 t2[3];
      #pragma unroll
      for (int i = 0; i < 3; ++i) t2[i] = (f32x4)0.0f;
      #pragma unroll
      for (int kt = 0; kt < 2; ++kt){
        bf16x8 a = ld8(&Sg[wave][tp][li][kt*32 + 8*lg]);
        #pragma unroll
        for (int nt = 0; nt < 3; ++nt) t2[nt] = MFMA16(a, lwF[nt][kt], t2[nt]);
      }
      #pragma unroll
      for (int nt = 0; nt < 3; ++nt){
        u16x4 w;
        #pragma unroll
        for (int r = 0; r < 4; ++r) w[r] = f2bf(t2[nt][r]);
        *(u16x4*)&t2T[half][nt*16 + li][t*16 + 4*lg] = w;
      }
    }
    __syncthreads();   // t2T complete (both halves)

    // ---- phase C: hu = gw x t2T (B-frags shared across tiles)
    f32x4 hu[2][3];
    #pragma unroll
    for (int tp = 0; tp < 2; ++tp)
      #pragma unroll
      for (int i = 0; i < 3; ++i) hu[tp][i] = (f32x4)0.0f;
    #pragma unroll
    for (int kt = 0; kt < 7; ++kt){
      bf16x8 b0 = ld8(&t2T[half][ 0 + li][kt*32 + 8*lg]);
      bf16x8 b1 = ld8(&t2T[half][16 + li][kt*32 + 8*lg]);
      bf16x8 b2 = ld8(&t2T[half][32 + li][kt*32 + 8*lg]);
      bf16x8 a0 = ld8(gA0 + kt*32);
      bf16x8 a1 = ld8(gA1 + kt*32);
      hu[0][0] = MFMA16(a0, b0, hu[0][0]);
      hu[0][1] = MFMA16(a0, b1, hu[0][1]);
      hu[0][2] = MFMA16(a0, b2, hu[0][2]);
      hu[1][0] = MFMA16(a1, b0, hu[1][0]);
      hu[1][1] = MFMA16(a1, b1, hu[1][1]);
      hu[1][2] = MFMA16(a1, b2, hu[1][2]);
    }
    #pragma unroll
    for (int tp = 0; tp < 2; ++tp){
      float s[4] = {0.f,0.f,0.f,0.f};
      #pragma unroll
      for (int nt = 0; nt < 3; ++nt)
        #pragma unroll
        for (int r = 0; r < 4; ++r){
          float v = fmaxf(hr[tp][nt][r] * hu[tp][nt][r], 1e-6f);
          hr[tp][nt][r] = v; s[r] += v;
        }
      #pragma unroll
      for (int r = 0; r < 4; ++r) s[r] = frcp(dpp_add16(s[r]));
      #pragma unroll
      for (int nt = 0; nt < 3; ++nt)
        #pragma unroll
        for (int r = 0; r < 4; ++r){
          hr[tp][nt][r] *= s[r];
          Sg[wave][tp][4*lg + r][nt*16 + li] = f2bf(hr[tp][nt][r]);
        }
    }
    lds_fence();
    #pragma unroll
    for (int tp = 0; tp < 2; ++tp){
      const int t = tt[tp];
      f32x4 hl[3];
      #pragma unroll
      for (int i = 0; i < 3; ++i) hl[i] = (f32x4)0.0f;
      #pragma unroll
      for (int kt = 0; kt < 2; ++kt){
        bf16x8 a = ld8(&Sg[wave][tp][li][kt*32 + 8*lg]);
        #pragma unroll
        for (int nt = 0; nt < 3; ++nt) hl[nt] = MFMA16(a, lwtF[nt][kt], hl[nt]);
      }
      #pragma unroll
      for (int nt = 0; nt < 3; ++nt){
        u16x4 w;
        #pragma unroll
        for (int r = 0; r < 4; ++r) w[r] = f2bf(hl[nt][r]);
        *(u16x4*)&hlT[half][nt*16 + li][t*16 + 4*lg] = w;
      }
    }
    __syncthreads();   // hlT complete for next iteration
  }

  // write back h (rows < 196 only; k_out reads only those rows/cols)
  uint16_t* __restrict__ hrow = h_b + (size_t)bh * SP * EP;
  #pragma unroll
  for (int tp = 0; tp < 2; ++tp){
    const int t = tt[tp];
    #pragma unroll
    for (int nt = 0; nt < 3; ++nt)
      #pragma unroll
      for (int r = 0; r < 4; ++r){
        int row = t*16 + 4*lg + r;
        if (row < NS)
          hrow[(size_t)row*EP + nt*16 + li] = f2bf(hr[tp][nt][r]);
      }
  }
}

// ---------------- output GEMM ----------------
// 8 waves; wave w: M-tile pair p=w>>2 (tiles 2p,2p+1), nt-range q=w&3
// (nts 6q..6q+5). B-frags shared across the 2 M-tiles (r9, validated).
__global__ __launch_bounds__(512) void k_out(const uint16_t* __restrict__ h_b,
    const uint16_t* __restrict__ ow_b, const float* __restrict__ obv,
    float* __restrict__ out){
  const int wave = threadIdx.x >> 6, lane = threadIdx.x & 63;
  const int lg = lane >> 4, li = lane & 15;
  const int p = wave >> 2, q = wave & 3;
  const int m0 = blockIdx.x * 64;
  f32x4 acc[2][6];
  #pragma unroll
  for (int mtl = 0; mtl < 2; ++mtl)
    #pragma unroll
    for (int i = 0; i < 6; ++i) acc[mtl][i] = (f32x4)0.0f;
  size_t rowbase[2];
  #pragma unroll
  for (int mtl = 0; mtl < 2; ++mtl){
    int m = m0 + (2*p + mtl)*16 + li;
    int b = m / NS, si = m - b*NS;
    rowbase[mtl] = ((size_t)b*NH*SP + si)*EP;
  }
  for (int kt = 0; kt < 12; ++kt){
    int ks = kt*32 + 8*lg;
    int hh = ks / NEH, f = ks - hh*NEH;
    size_t koff = (size_t)hh*SP*EP + f;
    bf16x8 a0 = ld8(h_b + rowbase[0] + koff);
    bf16x8 a1 = ld8(h_b + rowbase[1] + koff);
    #pragma unroll
    for (int n = 0; n < 6; ++n){
      bf16x8 bb = ld8(ow_b + (size_t)((6*q + n)*16 + li)*NF + kt*32 + 8*lg);
      acc[0][n] = MFMA16(a0, bb, acc[0][n]);
      acc[1][n] = MFMA16(a1, bb, acc[1][n]);
    }
  }
  #pragma unroll
  for (int mtl = 0; mtl < 2; ++mtl){
    #pragma unroll
    for (int n = 0; n < 6; ++n){
      int col = (6*q + n)*16 + li;
      float bias = obv[col];
      #pragma unroll
      for (int r = 0; r < 4; ++r)
        out[(size_t)(m0 + (2*p + mtl)*16 + 4*lg + r)*NF + col] = acc[mtl][n][r] + bias;
    }
  }
}

// ---------------- launch ----------------
extern "C" void kernel_launch(void* const* d_in, const int* in_sizes, int n_in,
                              void* d_out, int out_size, void* d_ws, size_t ws_size,
                              hipStream_t stream){
  const float* x   = (const float*)d_in[0];
  const float* h0  = (const float*)d_in[1];
  const float* ew  = (const float*)d_in[2];
  const float* eb  = (const float*)d_in[3];
  const float* lw  = (const float*)d_in[4];
  const float* gw  = (const float*)d_in[5];
  const float* ow  = (const float*)d_in[6];
  const float* obv = (const float*)d_in[7];
  float* out = (float*)d_out;

  char* w = (char*)d_ws;
  size_t o_inp = 0;
  size_t o_hb  = o_inp + (size_t)NBH*NT*64*12*2;   // inp_fm
  size_t o_gw  = o_hb  + (size_t)NBH*SP*EP*2;      // h_b
  size_t o_gwt = o_gw  + (size_t)NH*SP*SP*2;
  size_t o_lw  = o_gwt + (size_t)NH*SP*SP*2;
  size_t o_lwt = o_lw  + (size_t)EP*EP*2;
  size_t o_ew  = o_lwt + (size_t)EP*EP*2;
  size_t o_ow  = o_ew  + (size_t)NF*NF*2;
  size_t total = o_ow  + (size_t)NF*NF*2;
  if (ws_size < total) return;

  uint16_t* inp_fm = (uint16_t*)(w + o_inp);
  uint16_t* h_b    = (uint16_t*)(w + o_hb);
  uint16_t* gw_b   = (uint16_t*)(w + o_gw);
  uint16_t* gwt_b  = (uint16_t*)(w + o_gwt);
  uint16_t* lw_b   = (uint16_t*)(w + o_lw);
  uint16_t* lwt_b  = (uint16_t*)(w + o_lwt);
  uint16_t* ew_b   = (uint16_t*)(w + o_ew);
  uint16_t* ow_b   = (uint16_t*)(w + o_ow);

  k_prep_gw<<<(NH*SP*SP + 255)/256, 256, 0, stream>>>(gw, gw_b, gwt_b);
  k_prep_small<<<(NF*NF + 255)/256, 256, 0, stream>>>(lw, ew, ow, lw_b, lwt_b, ew_b, ow_b);
  k_embed<<<NBS/64, 512, 0, stream>>>(x, ew_b, eb, inp_fm);
  k_main<<<NBH/2, 896, 0, stream>>>(h0, gw_b, gwt_b, lw_b, lwt_b, inp_fm, h_b);
  k_out<<<NBS/64, 512, 0, stream>>>(h_b, ow_b, obv, out);
}

// Round 12
// 658.844 us; speedup vs baseline: 1.8146x; 1.8146x over previous
//
#include <hip/hip_runtime.h>
#include <stdint.h>

#define NB   256      // batch
#define NS   196      // seq len (= hidden seq)
#define NF   384      // in/out features
#define NH   8        // heads
#define NEH  48       // per-head dim
#define NIT  10
#define SP   224      // padded seq (14 tiles of 16)
#define EP   64       // padded per-head dim
#define NBH  2048     // NB*NH
#define NBS  50176    // NB*NS
#define NT   13       // inp tiles (rows<196 only)

using f32x4  = __attribute__((ext_vector_type(4))) float;
using u16x8  = __attribute__((ext_vector_type(8))) uint16_t;
using u16x4  = __attribute__((ext_vector_type(4))) uint16_t;
using bf16x8 = __attribute__((ext_vector_type(8))) __bf16;

static __device__ __forceinline__ float bf2f(uint16_t u){
  union { uint32_t u32; float f; } c; c.u32 = (uint32_t)u << 16; return c.f;
}
static __device__ __forceinline__ uint16_t f2bf(float f){
  __bf16 h = (__bf16)f;
  return __builtin_bit_cast(uint16_t, h);
}
static __device__ __forceinline__ float frcp(float f){
  return __builtin_amdgcn_rcpf(f);
}
static __device__ __forceinline__ bf16x8 ld8(const uint16_t* p){
  return __builtin_bit_cast(bf16x8, *(const u16x8*)p);
}
static __device__ __forceinline__ void lds_fence(){
  asm volatile("s_waitcnt lgkmcnt(0)" ::: "memory");
}
// 16-lane sum via DPP (4 VALU adds, no LDS traffic)
static __device__ __forceinline__ float dpp_add16(float x){
  int v = __builtin_bit_cast(int, x);
  x += __builtin_bit_cast(float, __builtin_amdgcn_update_dpp(0, v, 0xB1, 0xF, 0xF, false));
  v = __builtin_bit_cast(int, x);
  x += __builtin_bit_cast(float, __builtin_amdgcn_update_dpp(0, v, 0x4E, 0xF, 0xF, false));
  v = __builtin_bit_cast(int, x);
  x += __builtin_bit_cast(float, __builtin_amdgcn_update_dpp(0, v, 0x141, 0xF, 0xF, false));
  v = __builtin_bit_cast(int, x);
  x += __builtin_bit_cast(float, __builtin_amdgcn_update_dpp(0, v, 0x140, 0xF, 0xF, false));
  return x;
}
#define MFMA16(a,b,c) __builtin_amdgcn_mfma_f32_16x16x32_bf16((a),(b),(c),0,0,0)

// ---------------- prep kernels ----------------

__global__ void k_prep_gw(const float* __restrict__ gw, uint16_t* __restrict__ gw_b,
                          uint16_t* __restrict__ gwt_b){
  int idx = blockIdx.x * 256 + threadIdx.x;
  if (idx >= NH*SP*SP) return;
  int h = idx / (SP*SP);
  int r = (idx / SP) % SP;   // o
  int c = idx % SP;          // i
  float v = (r < NS && c < NS) ? gw[((size_t)h*NS + r)*NS + c] : 0.f;
  uint16_t bv = f2bf(v);
  gw_b[idx] = bv;
  gwt_b[((size_t)h*SP + c)*SP + r] = bv;
}

__global__ void k_prep_small(const float* __restrict__ lw, const float* __restrict__ ew,
                             const float* __restrict__ ow,
                             uint16_t* __restrict__ lw_b, uint16_t* __restrict__ lwt_b,
                             uint16_t* __restrict__ ew_b, uint16_t* __restrict__ ow_b){
  int idx = blockIdx.x * 256 + threadIdx.x;
  if (idx < EP*EP){
    int f = idx >> 6, e = idx & 63;
    float v = (f < NEH && e < NEH) ? lw[f*NEH + e] : 0.f;
    uint16_t bv = f2bf(v);
    lw_b[f*EP + e] = bv;     // [f][e]
    lwt_b[e*EP + f] = bv;    // [e][f]
  }
  if (idx < NF*NF){
    ew_b[idx] = f2bf(ew[idx]);
    ow_b[idx] = f2bf(ow[idx]);
  }
}

// ---------------- embed GEMM + input prep ----------------
// 8 waves; inp FRAGMENT-MAJOR: inp_fm[bh][t][lane][slot], slot=j*4+r.
// Stores VECTORIZED u16x4 (validated r9/r10).
__global__ __launch_bounds__(512) void k_embed(const float* __restrict__ x,
    const uint16_t* __restrict__ ew_b, const float* __restrict__ eb,
    uint16_t* __restrict__ inp_fm){
  const int wave = threadIdx.x >> 6, lane = threadIdx.x & 63;
  const int lg = lane >> 4, li = lane & 15;
  const int mt = wave >> 1, nh = wave & 1;
  const int m0 = blockIdx.x * 64 + mt * 16;
  f32x4 acc[12];
  #pragma unroll
  for (int i = 0; i < 12; ++i) acc[i] = (f32x4)0.0f;
  const float* ap = x + (size_t)(m0 + li) * NF + 8*lg;
  for (int kt = 0; kt < 12; ++kt){
    f32x4 a0 = *(const f32x4*)(ap + kt*32);
    f32x4 a1 = *(const f32x4*)(ap + kt*32 + 4);
    u16x8 au;
    #pragma unroll
    for (int j = 0; j < 4; ++j){ au[j] = f2bf(a0[j]); au[j+4] = f2bf(a1[j]); }
    bf16x8 a = __builtin_bit_cast(bf16x8, au);
    #pragma unroll
    for (int nt = 0; nt < 12; ++nt){
      bf16x8 b = ld8(ew_b + (size_t)((nh*12 + nt)*16 + li)*NF + kt*32 + 8*lg);
      acc[nt] = MFMA16(a, b, acc[nt]);
    }
  }
  const int mbase = m0 + 4*lg;
  const int b  = mbase / NS;
  const int si = mbase - b*NS;
  const int t  = si >> 4, wi = si & 15;
  const int lanep = (wi >> 2)*16 + li;
  #pragma unroll
  for (int hl = 0; hl < 4; ++hl){
    int hh = nh*4 + hl;
    float xec[3][4];
    float s[4] = {0.f, 0.f, 0.f, 0.f};
    #pragma unroll
    for (int j = 0; j < 3; ++j){
      int nt = hl*3 + j;
      float bias = eb[(nh*12 + nt)*16 + li];
      #pragma unroll
      for (int r = 0; r < 4; ++r){
        float v = fmaxf(acc[nt][r] + bias, 1e-6f);
        xec[j][r] = v; s[r] += v;
      }
    }
    #pragma unroll
    for (int r = 0; r < 4; ++r) s[r] = frcp(dpp_add16(s[r]));
    uint16_t* dst = inp_fm + ((size_t)((b*NH + hh)*NT + t)*64 + lanep)*12;
    #pragma unroll
    for (int j = 0; j < 3; ++j){
      u16x4 w;
      #pragma unroll
      for (int r = 0; r < 4; ++r) w[r] = f2bf(xec[j][r] * s[r]);
      *(u16x4*)(dst + j*4) = w;    // 8B-aligned (lanep*24 % 8 == 0)
    }
  }
}

// ---------------- main NNMF fixed-point kernel ----------------
// r10 configuration (measured 443 us; session optimum). 448 thr / 7 waves
// x 2 tiles = 14 tiles, UNCONDITIONAL dual-tile bodies. rec = gwT x (h x
// lw) via maintained hl; h fp32 + inp bf16 in regs; DPP row-sums; B-frags
// shared across the wave's two tiles. NOTE (r11 lesson): 448-thread blocks
// are the only geometry where the allocator grants ~120 VGPR; 512->96,
// 896->64 (spills). Do not change block size without re-checking VGPR.
__global__ __launch_bounds__(448) void k_main(
    const float*    __restrict__ h0,     // [B][NS][H][NEH]
    const uint16_t* __restrict__ gw_b,   // [H][SP][SP] (o,i)
    const uint16_t* __restrict__ gwt_b,  // [H][SP][SP] (i,o)
    const uint16_t* __restrict__ lw_b,   // [EP][EP] (f,e)
    const uint16_t* __restrict__ lwt_b,  // [EP][EP] (e,f)
    const uint16_t* __restrict__ inp_fm, // [BH][13][64][12]
    uint16_t* __restrict__ h_b)          // [BH][SP][EP] (for k_out)
{
  __shared__ __align__(16) uint16_t hlT[48][232];      // (h x lw)^T  [e][o]
  __shared__ __align__(16) uint16_t t2T[48][232];      // t2^T        [f][i]
  __shared__ __align__(16) uint16_t Sg[7][2][16][72];  // per-wave staging

  const int bh = blockIdx.x;
  const int b  = bh >> 3;
  const int hh = bh & 7;
  const int tid = threadIdx.x;
  const int wave = tid >> 6;
  const int lane = tid & 63;
  const int lg = lane >> 4;
  const int li = lane & 15;
  const int tt[2] = {wave, wave + 7};

  // zero staging K-pad cols 48..63 (never rewritten; kt=1 A-frag reads them)
  {
    u16x4 z = {0,0,0,0};
    *(u16x4*)&Sg[wave][0][li][48 + 4*lg] = z;
    *(u16x4*)&Sg[wave][1][li][48 + 4*lg] = z;
  }

  // local-weight B-fragments (constant across iterations)
  bf16x8 lwtF[3][2], lwF[3][2];
  #pragma unroll
  for (int nt = 0; nt < 3; ++nt)
    #pragma unroll
    for (int kt = 0; kt < 2; ++kt){
      lwtF[nt][kt] = ld8(lwt_b + (size_t)(nt*16 + li)*EP + kt*32 + 8*lg); // B[k=f][n=e]
      lwF [nt][kt] = ld8(lw_b  + (size_t)(nt*16 + li)*EP + kt*32 + 8*lg); // B[k=e][n=f]
    }

  // persistent inp fragments (iteration-invariant): pad tile 13 -> zeros
  u16x4 ip[2][3];
  #pragma unroll
  for (int tp = 0; tp < 2; ++tp){
    const int t = tt[tp];
    if (t < NT){
      const uint16_t* ipp = inp_fm + ((size_t)(bh*NT + t)*64 + lg*16 + li)*12;
      ip[tp][0] = *(const u16x4*)(ipp);
      ip[tp][1] = *(const u16x4*)(ipp + 4);
      ip[tp][2] = *(const u16x4*)(ipp + 8);
    } else {
      u16x4 z = {0,0,0,0};
      ip[tp][0] = z; ip[tp][1] = z; ip[tp][2] = z;
    }
  }

  // h init straight from h0 (fp32): fragment layout row=t*16+4lg+r,
  // col=nt*16+li; L1-normalize per row via dpp_add16; stage bf16 to Sg
  float hr[2][3][4];
  #pragma unroll
  for (int tp = 0; tp < 2; ++tp){
    const int t = tt[tp];
    float s[4] = {0.f,0.f,0.f,0.f};
    #pragma unroll
    for (int nt = 0; nt < 3; ++nt)
      #pragma unroll
      for (int r = 0; r < 4; ++r){
        int row = t*16 + 4*lg + r;
        float v = 0.f;
        if (row < NS)
          v = h0[(((size_t)(b*NS + row))*NH + hh)*NEH + nt*16 + li];
        hr[tp][nt][r] = v;
        s[r] += fabsf(v);
      }
    #pragma unroll
    for (int r = 0; r < 4; ++r) s[r] = frcp(fmaxf(dpp_add16(s[r]), 1e-12f));
    #pragma unroll
    for (int nt = 0; nt < 3; ++nt)
      #pragma unroll
      for (int r = 0; r < 4; ++r){
        hr[tp][nt][r] *= s[r];
        Sg[wave][tp][4*lg + r][nt*16 + li] = f2bf(hr[tp][nt][r]);
      }
  }
  lds_fence();
  // initial hl = h x lw -> hlT
  #pragma unroll
  for (int tp = 0; tp < 2; ++tp){
    const int t = tt[tp];
    f32x4 hl[3];
    #pragma unroll
    for (int i = 0; i < 3; ++i) hl[i] = (f32x4)0.0f;
    #pragma unroll
    for (int kt = 0; kt < 2; ++kt){
      bf16x8 a = ld8(&Sg[wave][tp][li][kt*32 + 8*lg]);
      #pragma unroll
      for (int nt = 0; nt < 3; ++nt) hl[nt] = MFMA16(a, lwtF[nt][kt], hl[nt]);
    }
    #pragma unroll
    for (int nt = 0; nt < 3; ++nt){
      u16x4 w;
      #pragma unroll
      for (int r = 0; r < 4; ++r) w[r] = f2bf(hl[nt][r]);
      *(u16x4*)&hlT[nt*16 + li][t*16 + 4*lg] = w;
    }
  }

  const uint16_t* __restrict__ gwh  = gw_b  + (size_t)hh * SP * SP;
  const uint16_t* __restrict__ gwth = gwt_b + (size_t)hh * SP * SP;
  const uint16_t* gA0t = gwth + (size_t)(tt[0]*16 + li)*SP + 8*lg;
  const uint16_t* gA1t = gwth + (size_t)(tt[1]*16 + li)*SP + 8*lg;
  const uint16_t* gA0  = gwh  + (size_t)(tt[0]*16 + li)*SP + 8*lg;
  const uint16_t* gA1  = gwh  + (size_t)(tt[1]*16 + li)*SP + 8*lg;
  __syncthreads();   // hlT ready

  for (int it = 0; it < NIT; ++it){
    // ---- phase B: rec = gwt x hlT (B-frags shared across tiles)
    f32x4 rec[2][3];
    #pragma unroll
    for (int tp = 0; tp < 2; ++tp)
      #pragma unroll
      for (int i = 0; i < 3; ++i) rec[tp][i] = (f32x4)0.0f;
    #pragma unroll
    for (int kt = 0; kt < 7; ++kt){
      bf16x8 b0 = ld8(&hlT[ 0 + li][kt*32 + 8*lg]);
      bf16x8 b1 = ld8(&hlT[16 + li][kt*32 + 8*lg]);
      bf16x8 b2 = ld8(&hlT[32 + li][kt*32 + 8*lg]);
      bf16x8 a0 = ld8(gA0t + kt*32);
      bf16x8 a1 = ld8(gA1t + kt*32);
      rec[0][0] = MFMA16(a0, b0, rec[0][0]);
      rec[0][1] = MFMA16(a0, b1, rec[0][1]);
      rec[0][2] = MFMA16(a0, b2, rec[0][2]);
      rec[1][0] = MFMA16(a1, b0, rec[1][0]);
      rec[1][1] = MFMA16(a1, b1, rec[1][1]);
      rec[1][2] = MFMA16(a1, b2, rec[1][2]);
    }
    #pragma unroll
    for (int tp = 0; tp < 2; ++tp){
      float s[4] = {0.f,0.f,0.f,0.f};
      float rv[3][4];
      #pragma unroll
      for (int nt = 0; nt < 3; ++nt)
        #pragma unroll
        for (int r = 0; r < 4; ++r){
          float v = fmaxf(rec[tp][nt][r], 1e-6f);
          rv[nt][r] = v; s[r] += v;
        }
      #pragma unroll
      for (int r = 0; r < 4; ++r) s[r] = dpp_add16(s[r]);
      #pragma unroll
      for (int r = 0; r < 4; ++r){
        Sg[wave][tp][4*lg + r][ 0 + li] = f2bf(bf2f(ip[tp][0][r]) * s[r] * frcp(rv[0][r]));
        Sg[wave][tp][4*lg + r][16 + li] = f2bf(bf2f(ip[tp][1][r]) * s[r] * frcp(rv[1][r]));
        Sg[wave][tp][4*lg + r][32 + li] = f2bf(bf2f(ip[tp][2][r]) * s[r] * frcp(rv[2][r]));
      }
    }
    lds_fence();
    #pragma unroll
    for (int tp = 0; tp < 2; ++tp){
      const int t = tt[tp];
      f32x4 t2[3];
      #pragma unroll
      for (int i = 0; i < 3; ++i) t2[i] = (f32x4)0.0f;
      #pragma unroll
      for (int kt = 0; kt < 2; ++kt){
        bf16x8 a = ld8(&Sg[wave][tp][li][kt*32 + 8*lg]);
        #pragma unroll
        for (int nt = 0; nt < 3; ++nt) t2[nt] = MFMA16(a, lwF[nt][kt], t2[nt]);
      }
      #pragma unroll
      for (int nt = 0; nt < 3; ++nt){
        u16x4 w;
        #pragma unroll
        for (int r = 0; r < 4; ++r) w[r] = f2bf(t2[nt][r]);
        *(u16x4*)&t2T[nt*16 + li][t*16 + 4*lg] = w;
      }
    }
    __syncthreads();   // t2T complete

    // ---- phase C: hu = gw x t2T (B-frags shared across tiles)
    f32x4 hu[2][3];
    #pragma unroll
    for (int tp = 0; tp < 2; ++tp)
      #pragma unroll
      for (int i = 0; i < 3; ++i) hu[tp][i] = (f32x4)0.0f;
    #pragma unroll
    for (int kt = 0; kt < 7; ++kt){
      bf16x8 b0 = ld8(&t2T[ 0 + li][kt*32 + 8*lg]);
      bf16x8 b1 = ld8(&t2T[16 + li][kt*32 + 8*lg]);
      bf16x8 b2 = ld8(&t2T[32 + li][kt*32 + 8*lg]);
      bf16x8 a0 = ld8(gA0 + kt*32);
      bf16x8 a1 = ld8(gA1 + kt*32);
      hu[0][0] = MFMA16(a0, b0, hu[0][0]);
      hu[0][1] = MFMA16(a0, b1, hu[0][1]);
      hu[0][2] = MFMA16(a0, b2, hu[0][2]);
      hu[1][0] = MFMA16(a1, b0, hu[1][0]);
      hu[1][1] = MFMA16(a1, b1, hu[1][1]);
      hu[1][2] = MFMA16(a1, b2, hu[1][2]);
    }
    #pragma unroll
    for (int tp = 0; tp < 2; ++tp){
      float s[4] = {0.f,0.f,0.f,0.f};
      #pragma unroll
      for (int nt = 0; nt < 3; ++nt)
        #pragma unroll
        for (int r = 0; r < 4; ++r){
          float v = fmaxf(hr[tp][nt][r] * hu[tp][nt][r], 1e-6f);
          hr[tp][nt][r] = v; s[r] += v;
        }
      #pragma unroll
      for (int r = 0; r < 4; ++r) s[r] = frcp(dpp_add16(s[r]));
      #pragma unroll
      for (int nt = 0; nt < 3; ++nt)
        #pragma unroll
        for (int r = 0; r < 4; ++r){
          hr[tp][nt][r] *= s[r];
          Sg[wave][tp][4*lg + r][nt*16 + li] = f2bf(hr[tp][nt][r]);
        }
    }
    lds_fence();
    #pragma unroll
    for (int tp = 0; tp < 2; ++tp){
      const int t = tt[tp];
      f32x4 hl[3];
      #pragma unroll
      for (int i = 0; i < 3; ++i) hl[i] = (f32x4)0.0f;
      #pragma unroll
      for (int kt = 0; kt < 2; ++kt){
        bf16x8 a = ld8(&Sg[wave][tp][li][kt*32 + 8*lg]);
        #pragma unroll
        for (int nt = 0; nt < 3; ++nt) hl[nt] = MFMA16(a, lwtF[nt][kt], hl[nt]);
      }
      #pragma unroll
      for (int nt = 0; nt < 3; ++nt){
        u16x4 w;
        #pragma unroll
        for (int r = 0; r < 4; ++r) w[r] = f2bf(hl[nt][r]);
        *(u16x4*)&hlT[nt*16 + li][t*16 + 4*lg] = w;
      }
    }
    __syncthreads();   // hlT complete for next iteration
  }

  // write back h (rows < 196 only; k_out reads only those rows/cols)
  uint16_t* __restrict__ hrow = h_b + (size_t)bh * SP * EP;
  #pragma unroll
  for (int tp = 0; tp < 2; ++tp){
    const int t = tt[tp];
    #pragma unroll
    for (int nt = 0; nt < 3; ++nt)
      #pragma unroll
      for (int r = 0; r < 4; ++r){
        int row = t*16 + 4*lg + r;
        if (row < NS)
          hrow[(size_t)row*EP + nt*16 + li] = f2bf(hr[tp][nt][r]);
      }
  }
}

// ---------------- output GEMM ----------------
// 8 waves; wave w: M-tile pair p=w>>2 (tiles 2p,2p+1), nt-range q=w&3
// (nts 6q..6q+5). B-frags shared across the 2 M-tiles (r9, validated).
__global__ __launch_bounds__(512) void k_out(const uint16_t* __restrict__ h_b,
    const uint16_t* __restrict__ ow_b, const float* __restrict__ obv,
    float* __restrict__ out){
  const int wave = threadIdx.x >> 6, lane = threadIdx.x & 63;
  const int lg = lane >> 4, li = lane & 15;
  const int p = wave >> 2, q = wave & 3;
  const int m0 = blockIdx.x * 64;
  f32x4 acc[2][6];
  #pragma unroll
  for (int mtl = 0; mtl < 2; ++mtl)
    #pragma unroll
    for (int i = 0; i < 6; ++i) acc[mtl][i] = (f32x4)0.0f;
  size_t rowbase[2];
  #pragma unroll
  for (int mtl = 0; mtl < 2; ++mtl){
    int m = m0 + (2*p + mtl)*16 + li;
    int b = m / NS, si = m - b*NS;
    rowbase[mtl] = ((size_t)b*NH*SP + si)*EP;
  }
  for (int kt = 0; kt < 12; ++kt){
    int ks = kt*32 + 8*lg;
    int hh = ks / NEH, f = ks - hh*NEH;
    size_t koff = (size_t)hh*SP*EP + f;
    bf16x8 a0 = ld8(h_b + rowbase[0] + koff);
    bf16x8 a1 = ld8(h_b + rowbase[1] + koff);
    #pragma unroll
    for (int n = 0; n < 6; ++n){
      bf16x8 bb = ld8(ow_b + (size_t)((6*q + n)*16 + li)*NF + kt*32 + 8*lg);
      acc[0][n] = MFMA16(a0, bb, acc[0][n]);
      acc[1][n] = MFMA16(a1, bb, acc[1][n]);
    }
  }
  #pragma unroll
  for (int mtl = 0; mtl < 2; ++mtl){
    #pragma unroll
    for (int n = 0; n < 6; ++n){
      int col = (6*q + n)*16 + li;
      float bias = obv[col];
      #pragma unroll
      for (int r = 0; r < 4; ++r)
        out[(size_t)(m0 + (2*p + mtl)*16 + 4*lg + r)*NF + col] = acc[mtl][n][r] + bias;
    }
  }
}

// ---------------- launch ----------------
extern "C" void kernel_launch(void* const* d_in, const int* in_sizes, int n_in,
                              void* d_out, int out_size, void* d_ws, size_t ws_size,
                              hipStream_t stream){
  const float* x   = (const float*)d_in[0];
  const float* h0  = (const float*)d_in[1];
  const float* ew  = (const float*)d_in[2];
  const float* eb  = (const float*)d_in[3];
  const float* lw  = (const float*)d_in[4];
  const float* gw  = (const float*)d_in[5];
  const float* ow  = (const float*)d_in[6];
  const float* obv = (const float*)d_in[7];
  float* out = (float*)d_out;

  char* w = (char*)d_ws;
  size_t o_inp = 0;
  size_t o_hb  = o_inp + (size_t)NBH*NT*64*12*2;   // inp_fm
  size_t o_gw  = o_hb  + (size_t)NBH*SP*EP*2;      // h_b
  size_t o_gwt = o_gw  + (size_t)NH*SP*SP*2;
  size_t o_lw  = o_gwt + (size_t)NH*SP*SP*2;
  size_t o_lwt = o_lw  + (size_t)EP*EP*2;
  size_t o_ew  = o_lwt + (size_t)EP*EP*2;
  size_t o_ow  = o_ew  + (size_t)NF*NF*2;
  size_t total = o_ow  + (size_t)NF*NF*2;
  if (ws_size < total) return;

  uint16_t* inp_fm = (uint16_t*)(w + o_inp);
  uint16_t* h_b    = (uint16_t*)(w + o_hb);
  uint16_t* gw_b   = (uint16_t*)(w + o_gw);
  uint16_t* gwt_b  = (uint16_t*)(w + o_gwt);
  uint16_t* lw_b   = (uint16_t*)(w + o_lw);
  uint16_t* lwt_b  = (uint16_t*)(w + o_lwt);
  uint16_t* ew_b   = (uint16_t*)(w + o_ew);
  uint16_t* ow_b   = (uint16_t*)(w + o_ow);

  k_prep_gw<<<(NH*SP*SP + 255)/256, 256, 0, stream>>>(gw, gw_b, gwt_b);
  k_prep_small<<<(NF*NF + 255)/256, 256, 0, stream>>>(lw, ew, ow, lw_b, lwt_b, ew_b, ow_b);
  k_embed<<<NBS/64, 512, 0, stream>>>(x, ew_b, eb, inp_fm);
  k_main<<<NBH, 448, 0, stream>>>(h0, gw_b, gwt_b, lw_b, lwt_b, inp_fm, h_b);
  k_out<<<NBS/64, 512, 0, stream>>>(h_b, ow_b, obv, out);
}

// Round 13
// 617.656 us; speedup vs baseline: 1.9356x; 1.0667x over previous
//
#include <hip/hip_runtime.h>
#include <stdint.h>

#define NB   256      // batch
#define NS   196      // seq len (= hidden seq)
#define NF   384      // in/out features
#define NH   8        // heads
#define NEH  48       // per-head dim
#define NIT  10
#define SP   224      // padded seq (14 tiles of 16)
#define EP   64       // padded per-head dim
#define NBH  2048     // NB*NH
#define NBS  50176    // NB*NS
#define NT   13       // inp tiles (rows<196 only)

using f32x4  = __attribute__((ext_vector_type(4))) float;
using u16x8  = __attribute__((ext_vector_type(8))) uint16_t;
using u16x4  = __attribute__((ext_vector_type(4))) uint16_t;
using bf16x8 = __attribute__((ext_vector_type(8))) __bf16;

static __device__ __forceinline__ float bf2f(uint16_t u){
  union { uint32_t u32; float f; } c; c.u32 = (uint32_t)u << 16; return c.f;
}
static __device__ __forceinline__ uint16_t f2bf(float f){
  __bf16 h = (__bf16)f;
  return __builtin_bit_cast(uint16_t, h);
}
static __device__ __forceinline__ float frcp(float f){
  return __builtin_amdgcn_rcpf(f);
}
static __device__ __forceinline__ bf16x8 ld8(const uint16_t* p){
  return __builtin_bit_cast(bf16x8, *(const u16x8*)p);
}
static __device__ __forceinline__ void lds_fence(){
  asm volatile("s_waitcnt lgkmcnt(0)" ::: "memory");
}
// 16-lane sum via DPP (4 VALU adds, no LDS traffic)
static __device__ __forceinline__ float dpp_add16(float x){
  int v = __builtin_bit_cast(int, x);
  x += __builtin_bit_cast(float, __builtin_amdgcn_update_dpp(0, v, 0xB1, 0xF, 0xF, false));
  v = __builtin_bit_cast(int, x);
  x += __builtin_bit_cast(float, __builtin_amdgcn_update_dpp(0, v, 0x4E, 0xF, 0xF, false));
  v = __builtin_bit_cast(int, x);
  x += __builtin_bit_cast(float, __builtin_amdgcn_update_dpp(0, v, 0x141, 0xF, 0xF, false));
  v = __builtin_bit_cast(int, x);
  x += __builtin_bit_cast(float, __builtin_amdgcn_update_dpp(0, v, 0x140, 0xF, 0xF, false));
  return x;
}
#define MFMA16(a,b,c) __builtin_amdgcn_mfma_f32_16x16x32_bf16((a),(b),(c),0,0,0)

// ---------------- prep kernels ----------------

__global__ void k_prep_gw(const float* __restrict__ gw, uint16_t* __restrict__ gw_b,
                          uint16_t* __restrict__ gwt_b){
  int idx = blockIdx.x * 256 + threadIdx.x;
  if (idx >= NH*SP*SP) return;
  int h = idx / (SP*SP);
  int r = (idx / SP) % SP;   // o
  int c = idx % SP;          // i
  float v = (r < NS && c < NS) ? gw[((size_t)h*NS + r)*NS + c] : 0.f;
  uint16_t bv = f2bf(v);
  gw_b[idx] = bv;
  gwt_b[((size_t)h*SP + c)*SP + r] = bv;
}

__global__ void k_prep_small(const float* __restrict__ lw, const float* __restrict__ ew,
                             const float* __restrict__ ow,
                             uint16_t* __restrict__ lw_b, uint16_t* __restrict__ lwt_b,
                             uint16_t* __restrict__ ew_b, uint16_t* __restrict__ ow_b){
  int idx = blockIdx.x * 256 + threadIdx.x;
  if (idx < EP*EP){
    int f = idx >> 6, e = idx & 63;
    float v = (f < NEH && e < NEH) ? lw[f*NEH + e] : 0.f;
    uint16_t bv = f2bf(v);
    lw_b[f*EP + e] = bv;     // [f][e]
    lwt_b[e*EP + f] = bv;    // [e][f]
  }
  if (idx < NF*NF){
    ew_b[idx] = f2bf(ew[idx]);
    ow_b[idx] = f2bf(ow[idx]);
  }
}

// ---------------- embed GEMM + input prep ----------------
// r13: k_out-mirror geometry. 8 waves; wave w: M-tile pair p=w>>2 (tiles
// 2p,2p+1), nt-range q=w&3 (nts 6q..6q+5 = heads 2q,2q+1). B-frags shared
// across the 2 M-tiles: 6 B-loads per 12 MFMAs (was 12) -- halves the B
// duplication (4 waves -> 2 waves per B column-range). acc 48 VGPR, same
// shape k_out validated at 96-VGPR/no-spill. Math order identical to r12.
// inp FRAGMENT-MAJOR: inp_fm[bh][t][lane][slot], slot=j*4+r; u16x4 stores
// (4-row m-groups 4-aligned in si, 196%4==0).
__global__ __launch_bounds__(512) void k_embed(const float* __restrict__ x,
    const uint16_t* __restrict__ ew_b, const float* __restrict__ eb,
    uint16_t* __restrict__ inp_fm){
  const int wave = threadIdx.x >> 6, lane = threadIdx.x & 63;
  const int lg = lane >> 4, li = lane & 15;
  const int p = wave >> 2, q = wave & 3;
  const int m0 = blockIdx.x * 64;
  f32x4 acc[2][6];
  #pragma unroll
  for (int mtl = 0; mtl < 2; ++mtl)
    #pragma unroll
    for (int i = 0; i < 6; ++i) acc[mtl][i] = (f32x4)0.0f;
  const float* ap0 = x + (size_t)(m0 + (2*p + 0)*16 + li)*NF + 8*lg;
  const float* ap1 = x + (size_t)(m0 + (2*p + 1)*16 + li)*NF + 8*lg;
  for (int kt = 0; kt < 12; ++kt){
    f32x4 a0lo = *(const f32x4*)(ap0 + kt*32);
    f32x4 a0hi = *(const f32x4*)(ap0 + kt*32 + 4);
    f32x4 a1lo = *(const f32x4*)(ap1 + kt*32);
    f32x4 a1hi = *(const f32x4*)(ap1 + kt*32 + 4);
    u16x8 au0, au1;
    #pragma unroll
    for (int j = 0; j < 4; ++j){
      au0[j] = f2bf(a0lo[j]); au0[j+4] = f2bf(a0hi[j]);
      au1[j] = f2bf(a1lo[j]); au1[j+4] = f2bf(a1hi[j]);
    }
    bf16x8 a0 = __builtin_bit_cast(bf16x8, au0);
    bf16x8 a1 = __builtin_bit_cast(bf16x8, au1);
    #pragma unroll
    for (int n = 0; n < 6; ++n){
      bf16x8 bb = ld8(ew_b + (size_t)((6*q + n)*16 + li)*NF + kt*32 + 8*lg);
      acc[0][n] = MFMA16(a0, bb, acc[0][n]);
      acc[1][n] = MFMA16(a1, bb, acc[1][n]);
    }
  }
  #pragma unroll
  for (int mtl = 0; mtl < 2; ++mtl){
    const int mbase = m0 + (2*p + mtl)*16 + 4*lg;
    const int b  = mbase / NS;
    const int si = mbase - b*NS;
    const int t  = si >> 4, wi = si & 15;
    const int lanep = (wi >> 2)*16 + li;
    #pragma unroll
    for (int hl = 0; hl < 2; ++hl){
      int hh = 2*q + hl;
      float xec[3][4];
      float s[4] = {0.f, 0.f, 0.f, 0.f};
      #pragma unroll
      for (int j = 0; j < 3; ++j){
        int n = hl*3 + j;
        float bias = eb[(6*q + n)*16 + li];
        #pragma unroll
        for (int r = 0; r < 4; ++r){
          float v = fmaxf(acc[mtl][n][r] + bias, 1e-6f);
          xec[j][r] = v; s[r] += v;
        }
      }
      #pragma unroll
      for (int r = 0; r < 4; ++r) s[r] = frcp(dpp_add16(s[r]));
      uint16_t* dst = inp_fm + ((size_t)((b*NH + hh)*NT + t)*64 + lanep)*12;
      #pragma unroll
      for (int j = 0; j < 3; ++j){
        u16x4 w;
        #pragma unroll
        for (int r = 0; r < 4; ++r) w[r] = f2bf(xec[j][r] * s[r]);
        *(u16x4*)(dst + j*4) = w;    // 8B-aligned (lanep*24 % 8 == 0)
      }
    }
  }
}

// ---------------- main NNMF fixed-point kernel ----------------
// r10 configuration (measured 443 us; session optimum). 448 thr / 7 waves
// x 2 tiles = 14 tiles, UNCONDITIONAL dual-tile bodies. rec = gwT x (h x
// lw) via maintained hl; h fp32 + inp bf16 in regs; DPP row-sums; B-frags
// shared across the wave's two tiles. NOTE (r11 lesson): 448-thread blocks
// are the only geometry where the allocator grants ~120 VGPR; 512->96,
// 896->64 (spills). Do not change block size without re-checking VGPR.
__global__ __launch_bounds__(448) void k_main(
    const float*    __restrict__ h0,     // [B][NS][H][NEH]
    const uint16_t* __restrict__ gw_b,   // [H][SP][SP] (o,i)
    const uint16_t* __restrict__ gwt_b,  // [H][SP][SP] (i,o)
    const uint16_t* __restrict__ lw_b,   // [EP][EP] (f,e)
    const uint16_t* __restrict__ lwt_b,  // [EP][EP] (e,f)
    const uint16_t* __restrict__ inp_fm, // [BH][13][64][12]
    uint16_t* __restrict__ h_b)          // [BH][SP][EP] (for k_out)
{
  __shared__ __align__(16) uint16_t hlT[48][232];      // (h x lw)^T  [e][o]
  __shared__ __align__(16) uint16_t t2T[48][232];      // t2^T        [f][i]
  __shared__ __align__(16) uint16_t Sg[7][2][16][72];  // per-wave staging

  const int bh = blockIdx.x;
  const int b  = bh >> 3;
  const int hh = bh & 7;
  const int tid = threadIdx.x;
  const int wave = tid >> 6;
  const int lane = tid & 63;
  const int lg = lane >> 4;
  const int li = lane & 15;
  const int tt[2] = {wave, wave + 7};

  // zero staging K-pad cols 48..63 (never rewritten; kt=1 A-frag reads them)
  {
    u16x4 z = {0,0,0,0};
    *(u16x4*)&Sg[wave][0][li][48 + 4*lg] = z;
    *(u16x4*)&Sg[wave][1][li][48 + 4*lg] = z;
  }

  // local-weight B-fragments (constant across iterations)
  bf16x8 lwtF[3][2], lwF[3][2];
  #pragma unroll
  for (int nt = 0; nt < 3; ++nt)
    #pragma unroll
    for (int kt = 0; kt < 2; ++kt){
      lwtF[nt][kt] = ld8(lwt_b + (size_t)(nt*16 + li)*EP + kt*32 + 8*lg); // B[k=f][n=e]
      lwF [nt][kt] = ld8(lw_b  + (size_t)(nt*16 + li)*EP + kt*32 + 8*lg); // B[k=e][n=f]
    }

  // persistent inp fragments (iteration-invariant): pad tile 13 -> zeros
  u16x4 ip[2][3];
  #pragma unroll
  for (int tp = 0; tp < 2; ++tp){
    const int t = tt[tp];
    if (t < NT){
      const uint16_t* ipp = inp_fm + ((size_t)(bh*NT + t)*64 + lg*16 + li)*12;
      ip[tp][0] = *(const u16x4*)(ipp);
      ip[tp][1] = *(const u16x4*)(ipp + 4);
      ip[tp][2] = *(const u16x4*)(ipp + 8);
    } else {
      u16x4 z = {0,0,0,0};
      ip[tp][0] = z; ip[tp][1] = z; ip[tp][2] = z;
    }
  }

  // h init straight from h0 (fp32): fragment layout row=t*16+4lg+r,
  // col=nt*16+li; L1-normalize per row via dpp_add16; stage bf16 to Sg
  float hr[2][3][4];
  #pragma unroll
  for (int tp = 0; tp < 2; ++tp){
    const int t = tt[tp];
    float s[4] = {0.f,0.f,0.f,0.f};
    #pragma unroll
    for (int nt = 0; nt < 3; ++nt)
      #pragma unroll
      for (int r = 0; r < 4; ++r){
        int row = t*16 + 4*lg + r;
        float v = 0.f;
        if (row < NS)
          v = h0[(((size_t)(b*NS + row))*NH + hh)*NEH + nt*16 + li];
        hr[tp][nt][r] = v;
        s[r] += fabsf(v);
      }
    #pragma unroll
    for (int r = 0; r < 4; ++r) s[r] = frcp(fmaxf(dpp_add16(s[r]), 1e-12f));
    #pragma unroll
    for (int nt = 0; nt < 3; ++nt)
      #pragma unroll
      for (int r = 0; r < 4; ++r){
        hr[tp][nt][r] *= s[r];
        Sg[wave][tp][4*lg + r][nt*16 + li] = f2bf(hr[tp][nt][r]);
      }
  }
  lds_fence();
  // initial hl = h x lw -> hlT
  #pragma unroll
  for (int tp = 0; tp < 2; ++tp){
    const int t = tt[tp];
    f32x4 hl[3];
    #pragma unroll
    for (int i = 0; i < 3; ++i) hl[i] = (f32x4)0.0f;
    #pragma unroll
    for (int kt = 0; kt < 2; ++kt){
      bf16x8 a = ld8(&Sg[wave][tp][li][kt*32 + 8*lg]);
      #pragma unroll
      for (int nt = 0; nt < 3; ++nt) hl[nt] = MFMA16(a, lwtF[nt][kt], hl[nt]);
    }
    #pragma unroll
    for (int nt = 0; nt < 3; ++nt){
      u16x4 w;
      #pragma unroll
      for (int r = 0; r < 4; ++r) w[r] = f2bf(hl[nt][r]);
      *(u16x4*)&hlT[nt*16 + li][t*16 + 4*lg] = w;
    }
  }

  const uint16_t* __restrict__ gwh  = gw_b  + (size_t)hh * SP * SP;
  const uint16_t* __restrict__ gwth = gwt_b + (size_t)hh * SP * SP;
  const uint16_t* gA0t = gwth + (size_t)(tt[0]*16 + li)*SP + 8*lg;
  const uint16_t* gA1t = gwth + (size_t)(tt[1]*16 + li)*SP + 8*lg;
  const uint16_t* gA0  = gwh  + (size_t)(tt[0]*16 + li)*SP + 8*lg;
  const uint16_t* gA1  = gwh  + (size_t)(tt[1]*16 + li)*SP + 8*lg;
  __syncthreads();   // hlT ready

  for (int it = 0; it < NIT; ++it){
    // ---- phase B: rec = gwt x hlT (B-frags shared across tiles)
    f32x4 rec[2][3];
    #pragma unroll
    for (int tp = 0; tp < 2; ++tp)
      #pragma unroll
      for (int i = 0; i < 3; ++i) rec[tp][i] = (f32x4)0.0f;
    #pragma unroll
    for (int kt = 0; kt < 7; ++kt){
      bf16x8 b0 = ld8(&hlT[ 0 + li][kt*32 + 8*lg]);
      bf16x8 b1 = ld8(&hlT[16 + li][kt*32 + 8*lg]);
      bf16x8 b2 = ld8(&hlT[32 + li][kt*32 + 8*lg]);
      bf16x8 a0 = ld8(gA0t + kt*32);
      bf16x8 a1 = ld8(gA1t + kt*32);
      rec[0][0] = MFMA16(a0, b0, rec[0][0]);
      rec[0][1] = MFMA16(a0, b1, rec[0][1]);
      rec[0][2] = MFMA16(a0, b2, rec[0][2]);
      rec[1][0] = MFMA16(a1, b0, rec[1][0]);
      rec[1][1] = MFMA16(a1, b1, rec[1][1]);
      rec[1][2] = MFMA16(a1, b2, rec[1][2]);
    }
    #pragma unroll
    for (int tp = 0; tp < 2; ++tp){
      float s[4] = {0.f,0.f,0.f,0.f};
      float rv[3][4];
      #pragma unroll
      for (int nt = 0; nt < 3; ++nt)
        #pragma unroll
        for (int r = 0; r < 4; ++r){
          float v = fmaxf(rec[tp][nt][r], 1e-6f);
          rv[nt][r] = v; s[r] += v;
        }
      #pragma unroll
      for (int r = 0; r < 4; ++r) s[r] = dpp_add16(s[r]);
      #pragma unroll
      for (int r = 0; r < 4; ++r){
        Sg[wave][tp][4*lg + r][ 0 + li] = f2bf(bf2f(ip[tp][0][r]) * s[r] * frcp(rv[0][r]));
        Sg[wave][tp][4*lg + r][16 + li] = f2bf(bf2f(ip[tp][1][r]) * s[r] * frcp(rv[1][r]));
        Sg[wave][tp][4*lg + r][32 + li] = f2bf(bf2f(ip[tp][2][r]) * s[r] * frcp(rv[2][r]));
      }
    }
    lds_fence();
    #pragma unroll
    for (int tp = 0; tp < 2; ++tp){
      const int t = tt[tp];
      f32x4 t2[3];
      #pragma unroll
      for (int i = 0; i < 3; ++i) t2[i] = (f32x4)0.0f;
      #pragma unroll
      for (int kt = 0; kt < 2; ++kt){
        bf16x8 a = ld8(&Sg[wave][tp][li][kt*32 + 8*lg]);
        #pragma unroll
        for (int nt = 0; nt < 3; ++nt) t2[nt] = MFMA16(a, lwF[nt][kt], t2[nt]);
      }
      #pragma unroll
      for (int nt = 0; nt < 3; ++nt){
        u16x4 w;
        #pragma unroll
        for (int r = 0; r < 4; ++r) w[r] = f2bf(t2[nt][r]);
        *(u16x4*)&t2T[nt*16 + li][t*16 + 4*lg] = w;
      }
    }
    __syncthreads();   // t2T complete

    // ---- phase C: hu = gw x t2T (B-frags shared across tiles)
    f32x4 hu[2][3];
    #pragma unroll
    for (int tp = 0; tp < 2; ++tp)
      #pragma unroll
      for (int i = 0; i < 3; ++i) hu[tp][i] = (f32x4)0.0f;
    #pragma unroll
    for (int kt = 0; kt < 7; ++kt){
      bf16x8 b0 = ld8(&t2T[ 0 + li][kt*32 + 8*lg]);
      bf16x8 b1 = ld8(&t2T[16 + li][kt*32 + 8*lg]);
      bf16x8 b2 = ld8(&t2T[32 + li][kt*32 + 8*lg]);
      bf16x8 a0 = ld8(gA0 + kt*32);
      bf16x8 a1 = ld8(gA1 + kt*32);
      hu[0][0] = MFMA16(a0, b0, hu[0][0]);
      hu[0][1] = MFMA16(a0, b1, hu[0][1]);
      hu[0][2] = MFMA16(a0, b2, hu[0][2]);
      hu[1][0] = MFMA16(a1, b0, hu[1][0]);
      hu[1][1] = MFMA16(a1, b1, hu[1][1]);
      hu[1][2] = MFMA16(a1, b2, hu[1][2]);
    }
    #pragma unroll
    for (int tp = 0; tp < 2; ++tp){
      float s[4] = {0.f,0.f,0.f,0.f};
      #pragma unroll
      for (int nt = 0; nt < 3; ++nt)
        #pragma unroll
        for (int r = 0; r < 4; ++r){
          float v = fmaxf(hr[tp][nt][r] * hu[tp][nt][r], 1e-6f);
          hr[tp][nt][r] = v; s[r] += v;
        }
      #pragma unroll
      for (int r = 0; r < 4; ++r) s[r] = frcp(dpp_add16(s[r]));
      #pragma unroll
      for (int nt = 0; nt < 3; ++nt)
        #pragma unroll
        for (int r = 0; r < 4; ++r){
          hr[tp][nt][r] *= s[r];
          Sg[wave][tp][4*lg + r][nt*16 + li] = f2bf(hr[tp][nt][r]);
        }
    }
    lds_fence();
    #pragma unroll
    for (int tp = 0; tp < 2; ++tp){
      const int t = tt[tp];
      f32x4 hl[3];
      #pragma unroll
      for (int i = 0; i < 3; ++i) hl[i] = (f32x4)0.0f;
      #pragma unroll
      for (int kt = 0; kt < 2; ++kt){
        bf16x8 a = ld8(&Sg[wave][tp][li][kt*32 + 8*lg]);
        #pragma unroll
        for (int nt = 0; nt < 3; ++nt) hl[nt] = MFMA16(a, lwtF[nt][kt], hl[nt]);
      }
      #pragma unroll
      for (int nt = 0; nt < 3; ++nt){
        u16x4 w;
        #pragma unroll
        for (int r = 0; r < 4; ++r) w[r] = f2bf(hl[nt][r]);
        *(u16x4*)&hlT[nt*16 + li][t*16 + 4*lg] = w;
      }
    }
    __syncthreads();   // hlT complete for next iteration
  }

  // write back h (rows < 196 only; k_out reads only those rows/cols)
  uint16_t* __restrict__ hrow = h_b + (size_t)bh * SP * EP;
  #pragma unroll
  for (int tp = 0; tp < 2; ++tp){
    const int t = tt[tp];
    #pragma unroll
    for (int nt = 0; nt < 3; ++nt)
      #pragma unroll
      for (int r = 0; r < 4; ++r){
        int row = t*16 + 4*lg + r;
        if (row < NS)
          hrow[(size_t)row*EP + nt*16 + li] = f2bf(hr[tp][nt][r]);
      }
  }
}

// ---------------- output GEMM ----------------
// 8 waves; wave w: M-tile pair p=w>>2 (tiles 2p,2p+1), nt-range q=w&3
// (nts 6q..6q+5). B-frags shared across the 2 M-tiles (r9, validated).
__global__ __launch_bounds__(512) void k_out(const uint16_t* __restrict__ h_b,
    const uint16_t* __restrict__ ow_b, const float* __restrict__ obv,
    float* __restrict__ out){
  const int wave = threadIdx.x >> 6, lane = threadIdx.x & 63;
  const int lg = lane >> 4, li = lane & 15;
  const int p = wave >> 2, q = wave & 3;
  const int m0 = blockIdx.x * 64;
  f32x4 acc[2][6];
  #pragma unroll
  for (int mtl = 0; mtl < 2; ++mtl)
    #pragma unroll
    for (int i = 0; i < 6; ++i) acc[mtl][i] = (f32x4)0.0f;
  size_t rowbase[2];
  #pragma unroll
  for (int mtl = 0; mtl < 2; ++mtl){
    int m = m0 + (2*p + mtl)*16 + li;
    int b = m / NS, si = m - b*NS;
    rowbase[mtl] = ((size_t)b*NH*SP + si)*EP;
  }
  for (int kt = 0; kt < 12; ++kt){
    int ks = kt*32 + 8*lg;
    int hh = ks / NEH, f = ks - hh*NEH;
    size_t koff = (size_t)hh*SP*EP + f;
    bf16x8 a0 = ld8(h_b + rowbase[0] + koff);
    bf16x8 a1 = ld8(h_b + rowbase[1] + koff);
    #pragma unroll
    for (int n = 0; n < 6; ++n){
      bf16x8 bb = ld8(ow_b + (size_t)((6*q + n)*16 + li)*NF + kt*32 + 8*lg);
      acc[0][n] = MFMA16(a0, bb, acc[0][n]);
      acc[1][n] = MFMA16(a1, bb, acc[1][n]);
    }
  }
  #pragma unroll
  for (int mtl = 0; mtl < 2; ++mtl){
    #pragma unroll
    for (int n = 0; n < 6; ++n){
      int col = (6*q + n)*16 + li;
      float bias = obv[col];
      #pragma unroll
      for (int r = 0; r < 4; ++r)
        out[(size_t)(m0 + (2*p + mtl)*16 + 4*lg + r)*NF + col] = acc[mtl][n][r] + bias;
    }
  }
}

// ---------------- launch ----------------
extern "C" void kernel_launch(void* const* d_in, const int* in_sizes, int n_in,
                              void* d_out, int out_size, void* d_ws, size_t ws_size,
                              hipStream_t stream){
  const float* x   = (const float*)d_in[0];
  const float* h0  = (const float*)d_in[1];
  const float* ew  = (const float*)d_in[2];
  const float* eb  = (const float*)d_in[3];
  const float* lw  = (const float*)d_in[4];
  const float* gw  = (const float*)d_in[5];
  const float* ow  = (const float*)d_in[6];
  const float* obv = (const float*)d_in[7];
  float* out = (float*)d_out;

  char* w = (char*)d_ws;
  size_t o_inp = 0;
  size_t o_hb  = o_inp + (size_t)NBH*NT*64*12*2;   // inp_fm
  size_t o_gw  = o_hb  + (size_t)NBH*SP*EP*2;      // h_b
  size_t o_gwt = o_gw  + (size_t)NH*SP*SP*2;
  size_t o_lw  = o_gwt + (size_t)NH*SP*SP*2;
  size_t o_lwt = o_lw  + (size_t)EP*EP*2;
  size_t o_ew  = o_lwt + (size_t)EP*EP*2;
  size_t o_ow  = o_ew  + (size_t)NF*NF*2;
  size_t total = o_ow  + (size_t)NF*NF*2;
  if (ws_size < total) return;

  uint16_t* inp_fm = (uint16_t*)(w + o_inp);
  uint16_t* h_b    = (uint16_t*)(w + o_hb);
  uint16_t* gw_b   = (uint16_t*)(w + o_gw);
  uint16_t* gwt_b  = (uint16_t*)(w + o_gwt);
  uint16_t* lw_b   = (uint16_t*)(w + o_lw);
  uint16_t* lwt_b  = (uint16_t*)(w + o_lwt);
  uint16_t* ew_b   = (uint16_t*)(w + o_ew);
  uint16_t* ow_b   = (uint16_t*)(w + o_ow);

  k_prep_gw<<<(NH*SP*SP + 255)/256, 256, 0, stream>>>(gw, gw_b, gwt_b);
  k_prep_small<<<(NF*NF + 255)/256, 256, 0, stream>>>(lw, ew, ow, lw_b, lwt_b, ew_b, ow_b);
  k_embed<<<NBS/64, 512, 0, stream>>>(x, ew_b, eb, inp_fm);
  k_main<<<NBH, 448, 0, stream>>>(h0, gw_b, gwt_b, lw_b, lwt_b, inp_fm, h_b);
  k_out<<<NBS/64, 512, 0, stream>>>(h_b, ow_b, obv, out);
}

// Round 14
// 605.915 us; speedup vs baseline: 1.9731x; 1.0194x over previous
//
#include <hip/hip_runtime.h>
#include <stdint.h>

#define NB   256      // batch
#define NS   196      // seq len (= hidden seq)
#define NF   384      // in/out features
#define NH   8        // heads
#define NEH  48       // per-head dim
#define NIT  10
#define SP   224      // padded seq (14 tiles of 16)
#define EP   64       // padded per-head dim
#define NBH  2048     // NB*NH
#define NBS  50176    // NB*NS
#define NT   13       // valid seq tiles (rows<196)

using f32x4  = __attribute__((ext_vector_type(4))) float;
using u16x8  = __attribute__((ext_vector_type(8))) uint16_t;
using u16x4  = __attribute__((ext_vector_type(4))) uint16_t;
using bf16x8 = __attribute__((ext_vector_type(8))) __bf16;

static __device__ __forceinline__ float bf2f(uint16_t u){
  union { uint32_t u32; float f; } c; c.u32 = (uint32_t)u << 16; return c.f;
}
static __device__ __forceinline__ uint16_t f2bf(float f){
  __bf16 h = (__bf16)f;
  return __builtin_bit_cast(uint16_t, h);
}
static __device__ __forceinline__ float frcp(float f){
  return __builtin_amdgcn_rcpf(f);
}
static __device__ __forceinline__ bf16x8 ld8(const uint16_t* p){
  return __builtin_bit_cast(bf16x8, *(const u16x8*)p);
}
static __device__ __forceinline__ void lds_fence(){
  asm volatile("s_waitcnt lgkmcnt(0)" ::: "memory");
}
// 16-lane sum via DPP (4 VALU adds, no LDS traffic)
static __device__ __forceinline__ float dpp_add16(float x){
  int v = __builtin_bit_cast(int, x);
  x += __builtin_bit_cast(float, __builtin_amdgcn_update_dpp(0, v, 0xB1, 0xF, 0xF, false));
  v = __builtin_bit_cast(int, x);
  x += __builtin_bit_cast(float, __builtin_amdgcn_update_dpp(0, v, 0x4E, 0xF, 0xF, false));
  v = __builtin_bit_cast(int, x);
  x += __builtin_bit_cast(float, __builtin_amdgcn_update_dpp(0, v, 0x141, 0xF, 0xF, false));
  v = __builtin_bit_cast(int, x);
  x += __builtin_bit_cast(float, __builtin_amdgcn_update_dpp(0, v, 0x140, 0xF, 0xF, false));
  return x;
}
#define MFMA16(a,b,c) __builtin_amdgcn_mfma_f32_16x16x32_bf16((a),(b),(c),0,0,0)

// ---------------- fused prep kernel (r14: one launch instead of two) ----
__global__ void k_prep(const float* __restrict__ gw, uint16_t* __restrict__ gw_b,
                       uint16_t* __restrict__ gwt_b,
                       const float* __restrict__ lw, const float* __restrict__ ew,
                       const float* __restrict__ ow,
                       uint16_t* __restrict__ lw_b, uint16_t* __restrict__ lwt_b,
                       uint16_t* __restrict__ ew_b, uint16_t* __restrict__ ow_b){
  int idx = blockIdx.x * 256 + threadIdx.x;
  if (idx < NH*SP*SP){
    int h = idx / (SP*SP);
    int r = (idx / SP) % SP;   // o
    int c = idx % SP;          // i
    float v = (r < NS && c < NS) ? gw[((size_t)h*NS + r)*NS + c] : 0.f;
    uint16_t bv = f2bf(v);
    gw_b[idx] = bv;
    gwt_b[((size_t)h*SP + c)*SP + r] = bv;
  }
  if (idx < EP*EP){
    int f = idx >> 6, e = idx & 63;
    float v = (f < NEH && e < NEH) ? lw[f*NEH + e] : 0.f;
    uint16_t bv = f2bf(v);
    lw_b[f*EP + e] = bv;     // [f][e]
    lwt_b[e*EP + f] = bv;    // [e][f]
  }
  if (idx < NF*NF){
    ew_b[idx] = f2bf(ew[idx]);
    ow_b[idx] = f2bf(ow[idx]);
  }
}

// ---------------- embed GEMM + input prep ----------------
// r13 geometry (validated): 8 waves; wave w: M-tile pair p=w>>2, nt-range
// q=w&3 (heads 2q,2q+1); B-frags shared across the 2 M-tiles.
// inp FRAGMENT-MAJOR: inp_fm[bh][t][lane][slot], slot=j*4+r; u16x4 stores.
__global__ __launch_bounds__(512) void k_embed(const float* __restrict__ x,
    const uint16_t* __restrict__ ew_b, const float* __restrict__ eb,
    uint16_t* __restrict__ inp_fm){
  const int wave = threadIdx.x >> 6, lane = threadIdx.x & 63;
  const int lg = lane >> 4, li = lane & 15;
  const int p = wave >> 2, q = wave & 3;
  const int m0 = blockIdx.x * 64;
  f32x4 acc[2][6];
  #pragma unroll
  for (int mtl = 0; mtl < 2; ++mtl)
    #pragma unroll
    for (int i = 0; i < 6; ++i) acc[mtl][i] = (f32x4)0.0f;
  const float* ap0 = x + (size_t)(m0 + (2*p + 0)*16 + li)*NF + 8*lg;
  const float* ap1 = x + (size_t)(m0 + (2*p + 1)*16 + li)*NF + 8*lg;
  for (int kt = 0; kt < 12; ++kt){
    f32x4 a0lo = *(const f32x4*)(ap0 + kt*32);
    f32x4 a0hi = *(const f32x4*)(ap0 + kt*32 + 4);
    f32x4 a1lo = *(const f32x4*)(ap1 + kt*32);
    f32x4 a1hi = *(const f32x4*)(ap1 + kt*32 + 4);
    u16x8 au0, au1;
    #pragma unroll
    for (int j = 0; j < 4; ++j){
      au0[j] = f2bf(a0lo[j]); au0[j+4] = f2bf(a0hi[j]);
      au1[j] = f2bf(a1lo[j]); au1[j+4] = f2bf(a1hi[j]);
    }
    bf16x8 a0 = __builtin_bit_cast(bf16x8, au0);
    bf16x8 a1 = __builtin_bit_cast(bf16x8, au1);
    #pragma unroll
    for (int n = 0; n < 6; ++n){
      bf16x8 bb = ld8(ew_b + (size_t)((6*q + n)*16 + li)*NF + kt*32 + 8*lg);
      acc[0][n] = MFMA16(a0, bb, acc[0][n]);
      acc[1][n] = MFMA16(a1, bb, acc[1][n]);
    }
  }
  #pragma unroll
  for (int mtl = 0; mtl < 2; ++mtl){
    const int mbase = m0 + (2*p + mtl)*16 + 4*lg;
    const int b  = mbase / NS;
    const int si = mbase - b*NS;
    const int t  = si >> 4, wi = si & 15;
    const int lanep = (wi >> 2)*16 + li;
    #pragma unroll
    for (int hl = 0; hl < 2; ++hl){
      int hh = 2*q + hl;
      float xec[3][4];
      float s[4] = {0.f, 0.f, 0.f, 0.f};
      #pragma unroll
      for (int j = 0; j < 3; ++j){
        int n = hl*3 + j;
        float bias = eb[(6*q + n)*16 + li];
        #pragma unroll
        for (int r = 0; r < 4; ++r){
          float v = fmaxf(acc[mtl][n][r] + bias, 1e-6f);
          xec[j][r] = v; s[r] += v;
        }
      }
      #pragma unroll
      for (int r = 0; r < 4; ++r) s[r] = frcp(dpp_add16(s[r]));
      uint16_t* dst = inp_fm + ((size_t)((b*NH + hh)*NT + t)*64 + lanep)*12;
      #pragma unroll
      for (int j = 0; j < 3; ++j){
        u16x4 w;
        #pragma unroll
        for (int r = 0; r < 4; ++r) w[r] = f2bf(xec[j][r] * s[r]);
        *(u16x4*)(dst + j*4) = w;    // 8B-aligned (lanep*24 % 8 == 0)
      }
    }
  }
}

// ---------------- main NNMF fixed-point kernel ----------------
// r10 configuration (443 us; session optimum) with r14 epilogue: h written
// FRAGMENT-MAJOR for k_out (h_fm[b][t][kt][wi][lg][8]), read back from the
// Sg staging which already holds the final bf16 h after the last phase C.
// Slot map: sg = hh*6 + sl (48 cols = 6 u16x8 slots -> kt=sg>>2, lg=sg&3);
// verified hh=sg/6, c=(sg%6)*8+j, k=sg*8+j. Values bit-identical to r13.
// NOTE (r11 lesson): 448-thread blocks are the only geometry where the
// allocator grants ~120 VGPR; 512->96, 896->64 (spills).
__global__ __launch_bounds__(448) void k_main(
    const float*    __restrict__ h0,     // [B][NS][H][NEH]
    const uint16_t* __restrict__ gw_b,   // [H][SP][SP] (o,i)
    const uint16_t* __restrict__ gwt_b,  // [H][SP][SP] (i,o)
    const uint16_t* __restrict__ lw_b,   // [EP][EP] (f,e)
    const uint16_t* __restrict__ lwt_b,  // [EP][EP] (e,f)
    const uint16_t* __restrict__ inp_fm, // [BH][13][64][12]
    uint16_t* __restrict__ h_fm)         // [B][13][12][16][32] (for k_out)
{
  __shared__ __align__(16) uint16_t hlT[48][232];      // (h x lw)^T  [e][o]
  __shared__ __align__(16) uint16_t t2T[48][232];      // t2^T        [f][i]
  __shared__ __align__(16) uint16_t Sg[7][2][16][72];  // per-wave staging

  const int bh = blockIdx.x;
  const int b  = bh >> 3;
  const int hh = bh & 7;
  const int tid = threadIdx.x;
  const int wave = tid >> 6;
  const int lane = tid & 63;
  const int lg = lane >> 4;
  const int li = lane & 15;
  const int tt[2] = {wave, wave + 7};

  // zero staging K-pad cols 48..63 (never rewritten; kt=1 A-frag reads them)
  {
    u16x4 z = {0,0,0,0};
    *(u16x4*)&Sg[wave][0][li][48 + 4*lg] = z;
    *(u16x4*)&Sg[wave][1][li][48 + 4*lg] = z;
  }

  // local-weight B-fragments (constant across iterations)
  bf16x8 lwtF[3][2], lwF[3][2];
  #pragma unroll
  for (int nt = 0; nt < 3; ++nt)
    #pragma unroll
    for (int kt = 0; kt < 2; ++kt){
      lwtF[nt][kt] = ld8(lwt_b + (size_t)(nt*16 + li)*EP + kt*32 + 8*lg); // B[k=f][n=e]
      lwF [nt][kt] = ld8(lw_b  + (size_t)(nt*16 + li)*EP + kt*32 + 8*lg); // B[k=e][n=f]
    }

  // persistent inp fragments (iteration-invariant): pad tile 13 -> zeros
  u16x4 ip[2][3];
  #pragma unroll
  for (int tp = 0; tp < 2; ++tp){
    const int t = tt[tp];
    if (t < NT){
      const uint16_t* ipp = inp_fm + ((size_t)(bh*NT + t)*64 + lg*16 + li)*12;
      ip[tp][0] = *(const u16x4*)(ipp);
      ip[tp][1] = *(const u16x4*)(ipp + 4);
      ip[tp][2] = *(const u16x4*)(ipp + 8);
    } else {
      u16x4 z = {0,0,0,0};
      ip[tp][0] = z; ip[tp][1] = z; ip[tp][2] = z;
    }
  }

  // h init straight from h0 (fp32): fragment layout row=t*16+4lg+r,
  // col=nt*16+li; L1-normalize per row via dpp_add16; stage bf16 to Sg
  float hr[2][3][4];
  #pragma unroll
  for (int tp = 0; tp < 2; ++tp){
    const int t = tt[tp];
    float s[4] = {0.f,0.f,0.f,0.f};
    #pragma unroll
    for (int nt = 0; nt < 3; ++nt)
      #pragma unroll
      for (int r = 0; r < 4; ++r){
        int row = t*16 + 4*lg + r;
        float v = 0.f;
        if (row < NS)
          v = h0[(((size_t)(b*NS + row))*NH + hh)*NEH + nt*16 + li];
        hr[tp][nt][r] = v;
        s[r] += fabsf(v);
      }
    #pragma unroll
    for (int r = 0; r < 4; ++r) s[r] = frcp(fmaxf(dpp_add16(s[r]), 1e-12f));
    #pragma unroll
    for (int nt = 0; nt < 3; ++nt)
      #pragma unroll
      for (int r = 0; r < 4; ++r){
        hr[tp][nt][r] *= s[r];
        Sg[wave][tp][4*lg + r][nt*16 + li] = f2bf(hr[tp][nt][r]);
      }
  }
  lds_fence();
  // initial hl = h x lw -> hlT
  #pragma unroll
  for (int tp = 0; tp < 2; ++tp){
    const int t = tt[tp];
    f32x4 hl[3];
    #pragma unroll
    for (int i = 0; i < 3; ++i) hl[i] = (f32x4)0.0f;
    #pragma unroll
    for (int kt = 0; kt < 2; ++kt){
      bf16x8 a = ld8(&Sg[wave][tp][li][kt*32 + 8*lg]);
      #pragma unroll
      for (int nt = 0; nt < 3; ++nt) hl[nt] = MFMA16(a, lwtF[nt][kt], hl[nt]);
    }
    #pragma unroll
    for (int nt = 0; nt < 3; ++nt){
      u16x4 w;
      #pragma unroll
      for (int r = 0; r < 4; ++r) w[r] = f2bf(hl[nt][r]);
      *(u16x4*)&hlT[nt*16 + li][t*16 + 4*lg] = w;
    }
  }

  const uint16_t* __restrict__ gwh  = gw_b  + (size_t)hh * SP * SP;
  const uint16_t* __restrict__ gwth = gwt_b + (size_t)hh * SP * SP;
  const uint16_t* gA0t = gwth + (size_t)(tt[0]*16 + li)*SP + 8*lg;
  const uint16_t* gA1t = gwth + (size_t)(tt[1]*16 + li)*SP + 8*lg;
  const uint16_t* gA0  = gwh  + (size_t)(tt[0]*16 + li)*SP + 8*lg;
  const uint16_t* gA1  = gwh  + (size_t)(tt[1]*16 + li)*SP + 8*lg;
  __syncthreads();   // hlT ready

  for (int it = 0; it < NIT; ++it){
    // ---- phase B: rec = gwt x hlT (B-frags shared across tiles)
    f32x4 rec[2][3];
    #pragma unroll
    for (int tp = 0; tp < 2; ++tp)
      #pragma unroll
      for (int i = 0; i < 3; ++i) rec[tp][i] = (f32x4)0.0f;
    #pragma unroll
    for (int kt = 0; kt < 7; ++kt){
      bf16x8 b0 = ld8(&hlT[ 0 + li][kt*32 + 8*lg]);
      bf16x8 b1 = ld8(&hlT[16 + li][kt*32 + 8*lg]);
      bf16x8 b2 = ld8(&hlT[32 + li][kt*32 + 8*lg]);
      bf16x8 a0 = ld8(gA0t + kt*32);
      bf16x8 a1 = ld8(gA1t + kt*32);
      rec[0][0] = MFMA16(a0, b0, rec[0][0]);
      rec[0][1] = MFMA16(a0, b1, rec[0][1]);
      rec[0][2] = MFMA16(a0, b2, rec[0][2]);
      rec[1][0] = MFMA16(a1, b0, rec[1][0]);
      rec[1][1] = MFMA16(a1, b1, rec[1][1]);
      rec[1][2] = MFMA16(a1, b2, rec[1][2]);
    }
    #pragma unroll
    for (int tp = 0; tp < 2; ++tp){
      float s[4] = {0.f,0.f,0.f,0.f};
      float rv[3][4];
      #pragma unroll
      for (int nt = 0; nt < 3; ++nt)
        #pragma unroll
        for (int r = 0; r < 4; ++r){
          float v = fmaxf(rec[tp][nt][r], 1e-6f);
          rv[nt][r] = v; s[r] += v;
        }
      #pragma unroll
      for (int r = 0; r < 4; ++r) s[r] = dpp_add16(s[r]);
      #pragma unroll
      for (int r = 0; r < 4; ++r){
        Sg[wave][tp][4*lg + r][ 0 + li] = f2bf(bf2f(ip[tp][0][r]) * s[r] * frcp(rv[0][r]));
        Sg[wave][tp][4*lg + r][16 + li] = f2bf(bf2f(ip[tp][1][r]) * s[r] * frcp(rv[1][r]));
        Sg[wave][tp][4*lg + r][32 + li] = f2bf(bf2f(ip[tp][2][r]) * s[r] * frcp(rv[2][r]));
      }
    }
    lds_fence();
    #pragma unroll
    for (int tp = 0; tp < 2; ++tp){
      const int t = tt[tp];
      f32x4 t2[3];
      #pragma unroll
      for (int i = 0; i < 3; ++i) t2[i] = (f32x4)0.0f;
      #pragma unroll
      for (int kt = 0; kt < 2; ++kt){
        bf16x8 a = ld8(&Sg[wave][tp][li][kt*32 + 8*lg]);
        #pragma unroll
        for (int nt = 0; nt < 3; ++nt) t2[nt] = MFMA16(a, lwF[nt][kt], t2[nt]);
      }
      #pragma unroll
      for (int nt = 0; nt < 3; ++nt){
        u16x4 w;
        #pragma unroll
        for (int r = 0; r < 4; ++r) w[r] = f2bf(t2[nt][r]);
        *(u16x4*)&t2T[nt*16 + li][t*16 + 4*lg] = w;
      }
    }
    __syncthreads();   // t2T complete

    // ---- phase C: hu = gw x t2T (B-frags shared across tiles)
    f32x4 hu[2][3];
    #pragma unroll
    for (int tp = 0; tp < 2; ++tp)
      #pragma unroll
      for (int i = 0; i < 3; ++i) hu[tp][i] = (f32x4)0.0f;
    #pragma unroll
    for (int kt = 0; kt < 7; ++kt){
      bf16x8 b0 = ld8(&t2T[ 0 + li][kt*32 + 8*lg]);
      bf16x8 b1 = ld8(&t2T[16 + li][kt*32 + 8*lg]);
      bf16x8 b2 = ld8(&t2T[32 + li][kt*32 + 8*lg]);
      bf16x8 a0 = ld8(gA0 + kt*32);
      bf16x8 a1 = ld8(gA1 + kt*32);
      hu[0][0] = MFMA16(a0, b0, hu[0][0]);
      hu[0][1] = MFMA16(a0, b1, hu[0][1]);
      hu[0][2] = MFMA16(a0, b2, hu[0][2]);
      hu[1][0] = MFMA16(a1, b0, hu[1][0]);
      hu[1][1] = MFMA16(a1, b1, hu[1][1]);
      hu[1][2] = MFMA16(a1, b2, hu[1][2]);
    }
    #pragma unroll
    for (int tp = 0; tp < 2; ++tp){
      float s[4] = {0.f,0.f,0.f,0.f};
      #pragma unroll
      for (int nt = 0; nt < 3; ++nt)
        #pragma unroll
        for (int r = 0; r < 4; ++r){
          float v = fmaxf(hr[tp][nt][r] * hu[tp][nt][r], 1e-6f);
          hr[tp][nt][r] = v; s[r] += v;
        }
      #pragma unroll
      for (int r = 0; r < 4; ++r) s[r] = frcp(dpp_add16(s[r]));
      #pragma unroll
      for (int nt = 0; nt < 3; ++nt)
        #pragma unroll
        for (int r = 0; r < 4; ++r){
          hr[tp][nt][r] *= s[r];
          Sg[wave][tp][4*lg + r][nt*16 + li] = f2bf(hr[tp][nt][r]);
        }
    }
    lds_fence();
    #pragma unroll
    for (int tp = 0; tp < 2; ++tp){
      const int t = tt[tp];
      f32x4 hl[3];
      #pragma unroll
      for (int i = 0; i < 3; ++i) hl[i] = (f32x4)0.0f;
      #pragma unroll
      for (int kt = 0; kt < 2; ++kt){
        bf16x8 a = ld8(&Sg[wave][tp][li][kt*32 + 8*lg]);
        #pragma unroll
        for (int nt = 0; nt < 3; ++nt) hl[nt] = MFMA16(a, lwtF[nt][kt], hl[nt]);
      }
      #pragma unroll
      for (int nt = 0; nt < 3; ++nt){
        u16x4 w;
        #pragma unroll
        for (int r = 0; r < 4; ++r) w[r] = f2bf(hl[nt][r]);
        *(u16x4*)&hlT[nt*16 + li][t*16 + 4*lg] = w;
      }
    }
    __syncthreads();   // hlT complete for next iteration
  }

  // write back h FRAGMENT-MAJOR for k_out, reading the final bf16 h from
  // Sg (staged during the last phase C; values identical to f2bf(hr)).
  // Per tile: 16 rows x 6 slots (u16x8); this block's slots are
  // sg = hh*6 + sl -> kt = sg>>2, lgo = sg&3.
  #pragma unroll
  for (int tp = 0; tp < 2; ++tp){
    const int t = tt[tp];
    if (t < NT){
      for (int idx = lane; idx < 96; idx += 64){
        int row = idx / 6, sl = idx - (idx/6)*6;
        if (t*16 + row < NS){
          int sg  = hh*6 + sl;
          int kt  = sg >> 2, lgo = sg & 3;
          u16x8 v = *(const u16x8*)&Sg[wave][tp][row][sl*8];
          *(u16x8*)(h_fm + ((((size_t)(b*NT + t))*12 + kt)*16 + row)*32 + 8*lgo) = v;
        }
      }
    }
  }
}

// ---------------- output GEMM ----------------
// 8 waves; wave w: M-tile pair p=w>>2 (tiles 2p,2p+1), nt-range q=w&3.
// r14: A-loads from fragment-major h_fm -- per (mtl,kt) the wave reads a
// fully contiguous 1 KB block (lane offset = wi*64B + lg*16B).
__global__ __launch_bounds__(512) void k_out(const uint16_t* __restrict__ h_fm,
    const uint16_t* __restrict__ ow_b, const float* __restrict__ obv,
    float* __restrict__ out){
  const int wave = threadIdx.x >> 6, lane = threadIdx.x & 63;
  const int lg = lane >> 4, li = lane & 15;
  const int p = wave >> 2, q = wave & 3;
  const int m0 = blockIdx.x * 64;
  f32x4 acc[2][6];
  #pragma unroll
  for (int mtl = 0; mtl < 2; ++mtl)
    #pragma unroll
    for (int i = 0; i < 6; ++i) acc[mtl][i] = (f32x4)0.0f;
  const uint16_t* abase[2];
  #pragma unroll
  for (int mtl = 0; mtl < 2; ++mtl){
    int m = m0 + (2*p + mtl)*16 + li;
    int b = m / NS, si = m - b*NS;
    int t = si >> 4, wi = si & 15;
    abase[mtl] = h_fm + ((size_t)(b*NT + t)*12*16 + wi)*32 + 8*lg;
  }
  for (int kt = 0; kt < 12; ++kt){
    bf16x8 a0 = ld8(abase[0] + kt*512);
    bf16x8 a1 = ld8(abase[1] + kt*512);
    #pragma unroll
    for (int n = 0; n < 6; ++n){
      bf16x8 bb = ld8(ow_b + (size_t)((6*q + n)*16 + li)*NF + kt*32 + 8*lg);
      acc[0][n] = MFMA16(a0, bb, acc[0][n]);
      acc[1][n] = MFMA16(a1, bb, acc[1][n]);
    }
  }
  #pragma unroll
  for (int mtl = 0; mtl < 2; ++mtl){
    #pragma unroll
    for (int n = 0; n < 6; ++n){
      int col = (6*q + n)*16 + li;
      float bias = obv[col];
      #pragma unroll
      for (int r = 0; r < 4; ++r)
        out[(size_t)(m0 + (2*p + mtl)*16 + 4*lg + r)*NF + col] = acc[mtl][n][r] + bias;
    }
  }
}

// ---------------- launch ----------------
extern "C" void kernel_launch(void* const* d_in, const int* in_sizes, int n_in,
                              void* d_out, int out_size, void* d_ws, size_t ws_size,
                              hipStream_t stream){
  const float* x   = (const float*)d_in[0];
  const float* h0  = (const float*)d_in[1];
  const float* ew  = (const float*)d_in[2];
  const float* eb  = (const float*)d_in[3];
  const float* lw  = (const float*)d_in[4];
  const float* gw  = (const float*)d_in[5];
  const float* ow  = (const float*)d_in[6];
  const float* obv = (const float*)d_in[7];
  float* out = (float*)d_out;

  char* w = (char*)d_ws;
  size_t o_inp = 0;
  size_t o_hb  = o_inp + (size_t)NBH*NT*64*12*2;   // inp_fm
  size_t o_gw  = o_hb  + (size_t)NBH*SP*EP*2;      // h_fm (fits: 40.9 <= 58.7 MB)
  size_t o_gwt = o_gw  + (size_t)NH*SP*SP*2;
  size_t o_lw  = o_gwt + (size_t)NH*SP*SP*2;
  size_t o_lwt = o_lw  + (size_t)EP*EP*2;
  size_t o_ew  = o_lwt + (size_t)EP*EP*2;
  size_t o_ow  = o_ew  + (size_t)NF*NF*2;
  size_t total = o_ow  + (size_t)NF*NF*2;
  if (ws_size < total) return;

  uint16_t* inp_fm = (uint16_t*)(w + o_inp);
  uint16_t* h_fm   = (uint16_t*)(w + o_hb);
  uint16_t* gw_b   = (uint16_t*)(w + o_gw);
  uint16_t* gwt_b  = (uint16_t*)(w + o_gwt);
  uint16_t* lw_b   = (uint16_t*)(w + o_lw);
  uint16_t* lwt_b  = (uint16_t*)(w + o_lwt);
  uint16_t* ew_b   = (uint16_t*)(w + o_ew);
  uint16_t* ow_b   = (uint16_t*)(w + o_ow);

  k_prep<<<(NH*SP*SP + 255)/256, 256, 0, stream>>>(gw, gw_b, gwt_b,
                                                   lw, ew, ow,
                                                   lw_b, lwt_b, ew_b, ow_b);
  k_embed<<<NBS/64, 512, 0, stream>>>(x, ew_b, eb, inp_fm);
  k_main<<<NBH, 448, 0, stream>>>(h0, gw_b, gwt_b, lw_b, lwt_b, inp_fm, h_fm);
  k_out<<<NBS/64, 512, 0, stream>>>(h_fm, ow_b, obv, out);
}